// Round 1
// baseline (390.042 us; speedup 1.0000x reference)
//
#include <hip/hip_runtime.h>

// ---- constants (problem sizes fixed by reference) ----
#define T_SEQ 2048
#define HID   2048
#define HQ    16
#define HKV   8
#define DH    128
#define NQKV  4096   // HQ*DH + 2*HKV*DH

typedef __attribute__((ext_vector_type(8))) __bf16 bf16x8;
typedef __attribute__((ext_vector_type(4))) float f32x4;
typedef __attribute__((ext_vector_type(8))) unsigned short ushort8;

__device__ __forceinline__ unsigned short f2bf(float f) {
  unsigned u = __builtin_bit_cast(unsigned, f);
  u += 0x7fffu + ((u >> 16) & 1u);
  return (unsigned short)(u >> 16);
}

__device__ __forceinline__ void gload_lds16(const void* g, void* l) {
  __builtin_amdgcn_global_load_lds((const __attribute__((address_space(1))) void*)g,
                                   (__attribute__((address_space(3))) void*)l, 16, 0, 0);
}

// ---- fp32 -> bf16 copy-convert (row-major preserved) ----
__global__ __launch_bounds__(256) void k_cvt(const float* __restrict__ in,
                                             unsigned short* __restrict__ out, int n4) {
  int i = blockIdx.x * 256 + threadIdx.x;
  if (i >= n4) return;
  float4 v = ((const float4*)in)[i];
  unsigned long long pk = (unsigned long long)f2bf(v.x)
                        | ((unsigned long long)f2bf(v.y) << 16)
                        | ((unsigned long long)f2bf(v.z) << 32)
                        | ((unsigned long long)f2bf(v.w) << 48);
  ((unsigned long long*)out)[i] = pk;
}

// ---- fp32 [R][C] (row stride ldin) -> bf16 [C][R] (row stride ldout); 64x64 tiles ----
__global__ __launch_bounds__(256) void k_transpose_cvt(const float* __restrict__ in,
                                                       unsigned short* __restrict__ out,
                                                       int ldin, int ldout) {
  __shared__ float tile[64][65];
  const int r0 = blockIdx.x * 64;
  const int c0 = blockIdx.y * 64;
  const int tid = threadIdx.x;
  {
    const int row = tid >> 4;          // 0..15
    const int cf  = (tid & 15) * 4;    // float4 col
#pragma unroll
    for (int k = 0; k < 4; k++) {
      const int r = row + k * 16;
      float4 v = *(const float4*)(in + (size_t)(r0 + r) * ldin + c0 + cf);
      tile[r][cf + 0] = v.x; tile[r][cf + 1] = v.y;
      tile[r][cf + 2] = v.z; tile[r][cf + 3] = v.w;
    }
  }
  __syncthreads();
  {
    const int c    = tid >> 3;         // 0..31
    const int rseg = (tid & 7) * 8;    // 8 elems
#pragma unroll
    for (int k = 0; k < 2; k++) {
      const int cc = c + k * 32;
      ushort8 ov;
#pragma unroll
      for (int e = 0; e < 8; e++) ov[e] = f2bf(tile[rseg + e][cc]);
      *(ushort8*)(out + (size_t)(c0 + cc) * ldout + r0 + rseg) = ov;
    }
  }
}

// ---- gate: lb[h][t] = log(clip(sigmoid(hidden[t] . gw[:,h] + gb[h]), 1e-8)) ----
__global__ __launch_bounds__(256) void k_gate(const float* __restrict__ hid,
                                              const float* __restrict__ gw,
                                              const float* __restrict__ gb,
                                              float* __restrict__ lb) {
  const int t = blockIdx.x * 4 + (threadIdx.x >> 6);
  const int lane = threadIdx.x & 63;
  float acc[8];
#pragma unroll
  for (int h = 0; h < 8; h++) acc[h] = 0.f;
  const float* hrow = hid + (size_t)t * HID;
  for (int i = lane; i < HID; i += 64) {
    const float hv = hrow[i];
    const float4 a = *(const float4*)(gw + (size_t)i * 8);
    const float4 b = *(const float4*)(gw + (size_t)i * 8 + 4);
    acc[0] += hv * a.x; acc[1] += hv * a.y; acc[2] += hv * a.z; acc[3] += hv * a.w;
    acc[4] += hv * b.x; acc[5] += hv * b.y; acc[6] += hv * b.z; acc[7] += hv * b.w;
  }
#pragma unroll
  for (int off = 32; off >= 1; off >>= 1)
#pragma unroll
    for (int h = 0; h < 8; h++) acc[h] += __shfl_xor(acc[h], off);
  if (lane == 0) {
#pragma unroll
    for (int h = 0; h < 8; h++) {
      const float x = acc[h] + gb[h];
      const float beta = 1.f / (1.f + __expf(-x));
      lb[(size_t)h * T_SEQ + t] = logf(fmaxf(beta, 1e-8f));
    }
  }
}

// ---- per-head RMSNorm + RoPE; qkv fp32 [T][4096] -> Qb bf16 [T][2048], Kb bf16 [T][1024] ----
__global__ __launch_bounds__(256) void k_norm_rope(const float* __restrict__ qkv,
                                                   const float* __restrict__ qw,
                                                   const float* __restrict__ kw,
                                                   const float* __restrict__ cosT,
                                                   const float* __restrict__ sinT,
                                                   unsigned short* __restrict__ Qb,
                                                   unsigned short* __restrict__ Kb) {
  const int t = blockIdx.x;
  const int wid = threadIdx.x >> 6, lane = threadIdx.x & 63;
  const float* row = qkv + (size_t)t * NQKV;
  const float c1 = cosT[t * DH + lane],      s1 = sinT[t * DH + lane];
  const float c2 = cosT[t * DH + 64 + lane], s2 = sinT[t * DH + 64 + lane];
  for (int hh = wid; hh < 24; hh += 4) {
    const int off = hh * DH;   // q heads: cols 0..2047 ; k heads: cols 2048..3071
    const float* x = row + off;
    const float x1 = x[lane], x2 = x[lane + 64];
    float ss = x1 * x1 + x2 * x2;
#pragma unroll
    for (int o = 32; o >= 1; o >>= 1) ss += __shfl_xor(ss, o);
    const float rinv = rsqrtf(ss * (1.f / DH) + 1e-6f);
    const float* wv = (hh < 16) ? qw : kw;
    const float y1 = x1 * rinv * wv[lane];
    const float y2 = x2 * rinv * wv[lane + 64];
    const float o1 = y1 * c1 - y2 * s1;
    const float o2 = y2 * c2 + y1 * s2;
    if (hh < 16) {
      Qb[(size_t)t * 2048 + hh * DH + lane]      = f2bf(o1);
      Qb[(size_t)t * 2048 + hh * DH + lane + 64] = f2bf(o2);
    } else {
      Kb[(size_t)t * 1024 + (hh - 16) * DH + lane]      = f2bf(o1);
      Kb[(size_t)t * 1024 + (hh - 16) * DH + lane + 64] = f2bf(o2);
    }
  }
}

// ---- bf16 GEMM: C[M][N] fp32 = A[M][K] * Bt[N][K]^T ; 128x128 tile, BK=32, 4 waves ----
__global__ __launch_bounds__(256) void k_gemm_bt(const unsigned short* __restrict__ A,
                                                 const unsigned short* __restrict__ Bt,
                                                 float* __restrict__ C, int K, int N) {
  __shared__ unsigned short lA[128 * 32];
  __shared__ unsigned short lB[128 * 32];
  const int tid = threadIdx.x;
  const int wid = tid >> 6, lane = tid & 63;
  const int lr = lane & 15, lg = lane >> 4;
  const int wr = wid >> 1, wc = wid & 1;
  const size_t tile_m = (size_t)blockIdx.x * 128, tile_n = (size_t)blockIdx.y * 128;

  f32x4 acc[4][4];
#pragma unroll
  for (int i = 0; i < 4; i++)
#pragma unroll
    for (int j = 0; j < 4; j++) acc[i][j] = (f32x4){0.f, 0.f, 0.f, 0.f};

  const int sr0 = wid * 32 + (lane >> 2);
  const int sc  = (lane & 3) * 16;  // bytes
  const char* gA0 = (const char*)A  + (tile_m + sr0) * (size_t)K * 2 + sc;
  const char* gA1 = gA0 + (size_t)16 * K * 2;
  const char* gB0 = (const char*)Bt + (tile_n + sr0) * (size_t)K * 2 + sc;
  const char* gB1 = gB0 + (size_t)16 * K * 2;
  char* lA0 = (char*)lA + wid * 2048;
  char* lA1 = lA0 + 1024;
  char* lB0 = (char*)lB + wid * 2048;
  char* lB1 = lB0 + 1024;

  for (int kb = 0; kb < K * 2; kb += 64) {  // kb in bytes
    gload_lds16(gA0 + kb, lA0);
    gload_lds16(gA1 + kb, lA1);
    gload_lds16(gB0 + kb, lB0);
    gload_lds16(gB1 + kb, lB1);
    __syncthreads();
    bf16x8 af[4], bfr[4];
#pragma unroll
    for (int mi = 0; mi < 4; mi++)
      af[mi] = *(const bf16x8*)&lA[(wr * 64 + mi * 16 + lr) * 32 + lg * 8];
#pragma unroll
    for (int ni = 0; ni < 4; ni++)
      bfr[ni] = *(const bf16x8*)&lB[(wc * 64 + ni * 16 + lr) * 32 + lg * 8];
#pragma unroll
    for (int mi = 0; mi < 4; mi++)
#pragma unroll
      for (int ni = 0; ni < 4; ni++)
        acc[mi][ni] = __builtin_amdgcn_mfma_f32_16x16x32_bf16(af[mi], bfr[ni], acc[mi][ni], 0, 0, 0);
    __syncthreads();
  }
#pragma unroll
  for (int mi = 0; mi < 4; mi++)
#pragma unroll
    for (int ni = 0; ni < 4; ni++)
#pragma unroll
      for (int r = 0; r < 4; r++)
        C[(tile_m + wr * 64 + mi * 16 + lg * 4 + r) * (size_t)N + tile_n + wc * 64 + ni * 16 + lr] =
            acc[mi][ni][r];
}

// ---- flash attention with retention bias; 4 waves x 16 q-rows, KV tiles of 32 ----
__global__ __launch_bounds__(256) void k_attn(const unsigned short* __restrict__ Q,
                                              const unsigned short* __restrict__ Kb,
                                              const unsigned short* __restrict__ Vt,
                                              const float* __restrict__ lb,
                                              unsigned short* __restrict__ O) {
  const int h = blockIdx.x;      // q head
  const int qblk = blockIdx.y;   // 64-row block
  const int kvh = h >> 1;        // G = 2
  const int tid = threadIdx.x;
  const int wid = tid >> 6, lane = tid & 63;
  const int lr = lane & 15, lg = lane >> 4;
  const int qb = qblk * 64 + wid * 16;

  __shared__ unsigned short plds[4][16 * 40];
  unsigned short* myp = plds[wid];

  bf16x8 qf[4];
  const unsigned short* Qp = Q + (size_t)(qb + lr) * 2048 + h * DH + lg * 8;
#pragma unroll
  for (int kc = 0; kc < 4; kc++) qf[kc] = *(const bf16x8*)(Qp + kc * 32);

  f32x4 o[8];
#pragma unroll
  for (int nc = 0; nc < 8; nc++) o[nc] = (f32x4){0.f, 0.f, 0.f, 0.f};
  float m[4], lsum[4];
#pragma unroll
  for (int r = 0; r < 4; r++) { m[r] = -1e30f; lsum[r] = 0.f; }

  const float scale = 0.08838834764831845f;  // 1/sqrt(128)
  const int ntiles = qblk * 2 + 2;
  const float* lbh = lb + (size_t)kvh * T_SEQ;
  const unsigned short* Kh = Kb + kvh * DH;
  const unsigned short* Vh = Vt + (size_t)kvh * DH * T_SEQ;

  for (int kt = 0; kt < ntiles; kt++) {
    const int kb = kt * 32;
    f32x4 sfr[2];
#pragma unroll
    for (int nf = 0; nf < 2; nf++) {
      f32x4 a = (f32x4){0.f, 0.f, 0.f, 0.f};
      const unsigned short* kp = Kh + (size_t)(kb + nf * 16 + lr) * 1024 + lg * 8;
#pragma unroll
      for (int kc = 0; kc < 4; kc++) {
        bf16x8 kf = *(const bf16x8*)(kp + kc * 32);
        a = __builtin_amdgcn_mfma_f32_16x16x32_bf16(qf[kc], kf, a, 0, 0, 0);
      }
      sfr[nf] = a;
    }
    // bias + causal mask + tile row-max
    float tm[4];
#pragma unroll
    for (int r = 0; r < 4; r++) tm[r] = -1e30f;
#pragma unroll
    for (int nf = 0; nf < 2; nf++) {
      const int j = kb + nf * 16 + lr;
      const float lbv = lbh[j];
#pragma unroll
      for (int r = 0; r < 4; r++) {
        const int i = qb + lg * 4 + r;
        float sv = sfr[nf][r] * scale + lbv * (float)(i - j);
        sv = (j <= i) ? sv : -1e30f;
        sfr[nf][r] = sv;
        tm[r] = fmaxf(tm[r], sv);
      }
    }
#pragma unroll
    for (int off = 8; off >= 1; off >>= 1)
#pragma unroll
      for (int r = 0; r < 4; r++) tm[r] = fmaxf(tm[r], __shfl_xor(tm[r], off));
    float corr[4], rs[4];
#pragma unroll
    for (int r = 0; r < 4; r++) {
      const float nm = fmaxf(m[r], tm[r]);
      corr[r] = __expf(m[r] - nm);
      m[r] = nm;
      const float p0 = __expf(sfr[0][r] - nm);
      const float p1 = __expf(sfr[1][r] - nm);
      sfr[0][r] = p0; sfr[1][r] = p1;
      rs[r] = p0 + p1;
    }
#pragma unroll
    for (int off = 8; off >= 1; off >>= 1)
#pragma unroll
      for (int r = 0; r < 4; r++) rs[r] += __shfl_xor(rs[r], off);
#pragma unroll
    for (int r = 0; r < 4; r++) lsum[r] = lsum[r] * corr[r] + rs[r];
#pragma unroll
    for (int nc = 0; nc < 8; nc++)
#pragma unroll
      for (int r = 0; r < 4; r++) o[nc][r] *= corr[r];
    // P (16x32) to LDS (D-layout write), read back as A-fragment
#pragma unroll
    for (int nf = 0; nf < 2; nf++)
#pragma unroll
      for (int r = 0; r < 4; r++)
        myp[(lg * 4 + r) * 40 + nf * 16 + lr] = f2bf(sfr[nf][r]);
    __syncthreads();
    const bf16x8 pa = *(const bf16x8*)&myp[lr * 40 + lg * 8];
#pragma unroll
    for (int nc = 0; nc < 8; nc++) {
      const unsigned short* vp = Vh + (size_t)(nc * 16 + lr) * T_SEQ + kb + lg * 8;
      const bf16x8 vf = *(const bf16x8*)vp;
      o[nc] = __builtin_amdgcn_mfma_f32_16x16x32_bf16(pa, vf, o[nc], 0, 0, 0);
    }
    __syncthreads();
  }
  float inv[4];
#pragma unroll
  for (int r = 0; r < 4; r++) inv[r] = 1.f / lsum[r];
#pragma unroll
  for (int nc = 0; nc < 8; nc++)
#pragma unroll
    for (int r = 0; r < 4; r++)
      O[(size_t)(qb + lg * 4 + r) * 2048 + h * DH + nc * 16 + lr] = f2bf(o[nc][r] * inv[r]);
}

extern "C" void kernel_launch(void* const* d_in, const int* in_sizes, int n_in,
                              void* d_out, int out_size, void* d_ws, size_t ws_size,
                              hipStream_t stream) {
  const float* hidden = (const float*)d_in[0];
  const float* Wq     = (const float*)d_in[1];
  const float* Wk     = (const float*)d_in[2];
  const float* Wv     = (const float*)d_in[3];
  const float* Wo     = (const float*)d_in[4];
  const float* qw     = (const float*)d_in[5];
  const float* kw     = (const float*)d_in[6];
  const float* gw     = (const float*)d_in[7];
  const float* gb     = (const float*)d_in[8];
  const float* cosT   = (const float*)d_in[9];
  const float* sinT   = (const float*)d_in[10];

  char* ws = (char*)d_ws;
  const size_t MB = (size_t)1 << 20;
  unsigned short* hbf   = (unsigned short*)(ws);              // 8 MB  bf16 hidden [2048][2048]
  unsigned short* BtQKV = (unsigned short*)(ws + 8 * MB);     // 16 MB bf16 [4096][2048] (Wq^T|Wk^T|Wv^T)
  unsigned short* WoT   = (unsigned short*)(ws + 24 * MB);    // 8 MB  bf16 [2048][2048] Wo^T
  float*          qkv   = (float*)(ws + 32 * MB);             // 32 MB fp32 [2048][4096]
  unsigned short* Qb    = (unsigned short*)(ws + 64 * MB);    // 8 MB  bf16 [2048][2048]
  unsigned short* Kbuf  = (unsigned short*)(ws + 72 * MB);    // 4 MB  bf16 [2048][1024]
  unsigned short* Vt    = (unsigned short*)(ws + 76 * MB);    // 4 MB  bf16 [8][128][2048]
  unsigned short* AO    = (unsigned short*)(ws + 80 * MB);    // 8 MB  bf16 [2048][2048]
  float*          lbuf  = (float*)(ws + 88 * MB);             // 64 KB fp32 [8][2048]

  k_cvt<<<4096, 256, 0, stream>>>(hidden, hbf, (HID * T_SEQ) / 4);
  k_transpose_cvt<<<dim3(32, 32), 256, 0, stream>>>(Wq, BtQKV, 2048, 2048);
  k_transpose_cvt<<<dim3(32, 16), 256, 0, stream>>>(Wk, BtQKV + (size_t)2048 * 2048, 1024, 2048);
  k_transpose_cvt<<<dim3(32, 16), 256, 0, stream>>>(Wv, BtQKV + (size_t)3072 * 2048, 1024, 2048);
  k_transpose_cvt<<<dim3(32, 32), 256, 0, stream>>>(Wo, WoT, 2048, 2048);
  k_gate<<<512, 256, 0, stream>>>(hidden, gw, gb, lbuf);
  k_gemm_bt<<<dim3(16, 32), 256, 0, stream>>>(hbf, BtQKV, qkv, 2048, 4096);
  k_norm_rope<<<2048, 256, 0, stream>>>(qkv, qw, kw, cosT, sinT, Qb, Kbuf);
  k_transpose_cvt<<<dim3(32, 16), 256, 0, stream>>>(qkv + 3072, Vt, 4096, 2048);
  k_attn<<<dim3(16, 32), 256, 0, stream>>>(Qb, Kbuf, Vt, lbuf, AO);
  k_gemm_bt<<<dim3(16, 16), 256, 0, stream>>>(AO, WoT, (float*)d_out, 2048, 2048);
}

// Round 2
// 384.997 us; speedup vs baseline: 1.0131x; 1.0131x over previous
//
#include <hip/hip_runtime.h>

// ---- constants (problem sizes fixed by reference) ----
#define T_SEQ 2048
#define HID   2048
#define HQ    16
#define HKV   8
#define DH    128
#define NQKV  4096   // HQ*DH + 2*HKV*DH

#define QSCALE (0.08838834764831845f * 1.4426950408889634f)  // 1/sqrt(128) * log2(e)

typedef __attribute__((ext_vector_type(8))) __bf16 bf16x8;
typedef __attribute__((ext_vector_type(4))) float f32x4;
typedef __attribute__((ext_vector_type(8))) unsigned short ushort8;

__device__ __forceinline__ unsigned short f2bf(float f) {
  unsigned u = __builtin_bit_cast(unsigned, f);
  u += 0x7fffu + ((u >> 16) & 1u);
  return (unsigned short)(u >> 16);
}

__device__ __forceinline__ void gload_lds16(const void* g, void* l) {
  __builtin_amdgcn_global_load_lds((const __attribute__((address_space(1))) void*)g,
                                   (__attribute__((address_space(3))) void*)l, 16, 0, 0);
}

// ---- fp32 -> bf16 copy-convert (row-major preserved) ----
__global__ __launch_bounds__(256) void k_cvt(const float* __restrict__ in,
                                             unsigned short* __restrict__ out, int n4) {
  int i = blockIdx.x * 256 + threadIdx.x;
  if (i >= n4) return;
  float4 v = ((const float4*)in)[i];
  unsigned long long pk = (unsigned long long)f2bf(v.x)
                        | ((unsigned long long)f2bf(v.y) << 16)
                        | ((unsigned long long)f2bf(v.z) << 32)
                        | ((unsigned long long)f2bf(v.w) << 48);
  ((unsigned long long*)out)[i] = pk;
}

// ---- fp32 [R][C] (row stride ldin) -> bf16 [C][R] (row stride ldout); 64x64 tiles ----
__global__ __launch_bounds__(256) void k_transpose_cvt(const float* __restrict__ in,
                                                       unsigned short* __restrict__ out,
                                                       int ldin, int ldout) {
  __shared__ float tile[64][65];
  const int r0 = blockIdx.x * 64;
  const int c0 = blockIdx.y * 64;
  const int tid = threadIdx.x;
  {
    const int row = tid >> 4;          // 0..15
    const int cf  = (tid & 15) * 4;    // float4 col
#pragma unroll
    for (int k = 0; k < 4; k++) {
      const int r = row + k * 16;
      float4 v = *(const float4*)(in + (size_t)(r0 + r) * ldin + c0 + cf);
      tile[r][cf + 0] = v.x; tile[r][cf + 1] = v.y;
      tile[r][cf + 2] = v.z; tile[r][cf + 3] = v.w;
    }
  }
  __syncthreads();
  {
    const int c    = tid >> 3;         // 0..31
    const int rseg = (tid & 7) * 8;    // 8 elems
#pragma unroll
    for (int k = 0; k < 2; k++) {
      const int cc = c + k * 32;
      ushort8 ov;
#pragma unroll
      for (int e = 0; e < 8; e++) ov[e] = f2bf(tile[rseg + e][cc]);
      *(ushort8*)(out + (size_t)(c0 + cc) * ldout + r0 + rseg) = ov;
    }
  }
}

// ---- gate: lb[h][t] = log2(clip(sigmoid(hidden[t] . gw[:,h] + gb[h]), 1e-8)) ----
__global__ __launch_bounds__(256) void k_gate(const float* __restrict__ hid,
                                              const float* __restrict__ gw,
                                              const float* __restrict__ gb,
                                              float* __restrict__ lb) {
  const int t = blockIdx.x * 4 + (threadIdx.x >> 6);
  const int lane = threadIdx.x & 63;
  float acc[8];
#pragma unroll
  for (int h = 0; h < 8; h++) acc[h] = 0.f;
  const float* hrow = hid + (size_t)t * HID;
  for (int i = lane; i < HID; i += 64) {
    const float hv = hrow[i];
    const float4 a = *(const float4*)(gw + (size_t)i * 8);
    const float4 b = *(const float4*)(gw + (size_t)i * 8 + 4);
    acc[0] += hv * a.x; acc[1] += hv * a.y; acc[2] += hv * a.z; acc[3] += hv * a.w;
    acc[4] += hv * b.x; acc[5] += hv * b.y; acc[6] += hv * b.z; acc[7] += hv * b.w;
  }
#pragma unroll
  for (int off = 32; off >= 1; off >>= 1)
#pragma unroll
    for (int h = 0; h < 8; h++) acc[h] += __shfl_xor(acc[h], off);
  if (lane == 0) {
#pragma unroll
    for (int h = 0; h < 8; h++) {
      const float x = acc[h] + gb[h];
      const float beta = 1.f / (1.f + __expf(-x));
      lb[(size_t)h * T_SEQ + t] = log2f(fmaxf(beta, 1e-8f));   // log2 domain
    }
  }
}

// ---- per-head RMSNorm + RoPE; qkv fp32 [T][4096] -> Qb bf16 [T][2048] (pre-scaled), Kb bf16 [T][1024] ----
__global__ __launch_bounds__(256) void k_norm_rope(const float* __restrict__ qkv,
                                                   const float* __restrict__ qw,
                                                   const float* __restrict__ kw,
                                                   const float* __restrict__ cosT,
                                                   const float* __restrict__ sinT,
                                                   unsigned short* __restrict__ Qb,
                                                   unsigned short* __restrict__ Kb) {
  const int t = blockIdx.x;
  const int wid = threadIdx.x >> 6, lane = threadIdx.x & 63;
  const float* row = qkv + (size_t)t * NQKV;
  const float c1 = cosT[t * DH + lane],      s1 = sinT[t * DH + lane];
  const float c2 = cosT[t * DH + 64 + lane], s2 = sinT[t * DH + 64 + lane];
  for (int hh = wid; hh < 24; hh += 4) {
    const int off = hh * DH;   // q heads: cols 0..2047 ; k heads: cols 2048..3071
    const float* x = row + off;
    const float x1 = x[lane], x2 = x[lane + 64];
    float ss = x1 * x1 + x2 * x2;
#pragma unroll
    for (int o = 32; o >= 1; o >>= 1) ss += __shfl_xor(ss, o);
    const float rinv = rsqrtf(ss * (1.f / DH) + 1e-6f);
    const float* wv = (hh < 16) ? qw : kw;
    const float y1 = x1 * rinv * wv[lane];
    const float y2 = x2 * rinv * wv[lane + 64];
    float o1 = y1 * c1 - y2 * s1;
    float o2 = y2 * c2 + y1 * s2;
    if (hh < 16) {
      o1 *= QSCALE; o2 *= QSCALE;   // fold attn scale + log2e into Q
      Qb[(size_t)t * 2048 + hh * DH + lane]      = f2bf(o1);
      Qb[(size_t)t * 2048 + hh * DH + lane + 64] = f2bf(o2);
    } else {
      Kb[(size_t)t * 1024 + (hh - 16) * DH + lane]      = f2bf(o1);
      Kb[(size_t)t * 1024 + (hh - 16) * DH + lane + 64] = f2bf(o2);
    }
  }
}

// ---- bf16 GEMM: C[M][N] fp32 = A[M][K] * Bt[N][K]^T ; 128x128 tile, BK=32, 4 waves ----
__global__ __launch_bounds__(256) void k_gemm_bt(const unsigned short* __restrict__ A,
                                                 const unsigned short* __restrict__ Bt,
                                                 float* __restrict__ C, int K, int N) {
  __shared__ unsigned short lA[128 * 32];
  __shared__ unsigned short lB[128 * 32];
  const int tid = threadIdx.x;
  const int wid = tid >> 6, lane = tid & 63;
  const int lr = lane & 15, lg = lane >> 4;
  const int wr = wid >> 1, wc = wid & 1;
  const size_t tile_m = (size_t)blockIdx.x * 128, tile_n = (size_t)blockIdx.y * 128;

  f32x4 acc[4][4];
#pragma unroll
  for (int i = 0; i < 4; i++)
#pragma unroll
    for (int j = 0; j < 4; j++) acc[i][j] = (f32x4){0.f, 0.f, 0.f, 0.f};

  const int sr0 = wid * 32 + (lane >> 2);
  const int sc  = (lane & 3) * 16;  // bytes
  const char* gA0 = (const char*)A  + (tile_m + sr0) * (size_t)K * 2 + sc;
  const char* gA1 = gA0 + (size_t)16 * K * 2;
  const char* gB0 = (const char*)Bt + (tile_n + sr0) * (size_t)K * 2 + sc;
  const char* gB1 = gB0 + (size_t)16 * K * 2;
  char* lA0 = (char*)lA + wid * 2048;
  char* lA1 = lA0 + 1024;
  char* lB0 = (char*)lB + wid * 2048;
  char* lB1 = lB0 + 1024;

  for (int kb = 0; kb < K * 2; kb += 64) {  // kb in bytes
    gload_lds16(gA0 + kb, lA0);
    gload_lds16(gA1 + kb, lA1);
    gload_lds16(gB0 + kb, lB0);
    gload_lds16(gB1 + kb, lB1);
    __syncthreads();
    bf16x8 af[4], bfr[4];
#pragma unroll
    for (int mi = 0; mi < 4; mi++)
      af[mi] = *(const bf16x8*)&lA[(wr * 64 + mi * 16 + lr) * 32 + lg * 8];
#pragma unroll
    for (int ni = 0; ni < 4; ni++)
      bfr[ni] = *(const bf16x8*)&lB[(wc * 64 + ni * 16 + lr) * 32 + lg * 8];
#pragma unroll
    for (int mi = 0; mi < 4; mi++)
#pragma unroll
      for (int ni = 0; ni < 4; ni++)
        acc[mi][ni] = __builtin_amdgcn_mfma_f32_16x16x32_bf16(af[mi], bfr[ni], acc[mi][ni], 0, 0, 0);
    __syncthreads();
  }
#pragma unroll
  for (int mi = 0; mi < 4; mi++)
#pragma unroll
    for (int ni = 0; ni < 4; ni++)
#pragma unroll
      for (int r = 0; r < 4; r++)
        C[(tile_m + wr * 64 + mi * 16 + lg * 4 + r) * (size_t)N + tile_n + wc * 64 + ni * 16 + lr] =
            acc[mi][ni][r];
}

// ---- flash attention, wave-independent: each wave = (head, 16 q-rows), KV tiles of 64,
//      reverse (diagonal-first) iteration, register K prefetch, no barriers ----
__global__ __launch_bounds__(256, 2) void k_attn(const unsigned short* __restrict__ Q,
                                                 const unsigned short* __restrict__ Kb,
                                                 const unsigned short* __restrict__ Vt,
                                                 const float* __restrict__ lb,
                                                 unsigned short* __restrict__ O) {
  const int tid = threadIdx.x;
  const int wid = tid >> 6, lane = tid & 63;
  const int u = blockIdx.x * 4 + wid;   // wave-unit 0..2047
  const int h = u >> 7;                 // q head 0..15
  const int c = u & 127;                // 16-row chunk 0..127
  const int qb = c * 16;
  const int lr = lane & 15, lg = lane >> 4;
  const int kvh = h >> 1;               // G = 2

  __shared__ unsigned short plds[4][16 * 72];
  unsigned short* myp = plds[wid];

  // Q fragments (Q pre-scaled by 1/sqrt(D)*log2e)
  bf16x8 qf[4];
  {
    const unsigned short* Qp = Q + (size_t)(qb + lr) * 2048 + h * DH + lg * 8;
#pragma unroll
    for (int kc = 0; kc < 4; kc++) qf[kc] = *(const bf16x8*)(Qp + kc * 32);
  }

  f32x4 o[8];
#pragma unroll
  for (int nc = 0; nc < 8; nc++) o[nc] = (f32x4){0.f, 0.f, 0.f, 0.f};
  float m[4], lsum[4];
#pragma unroll
  for (int r = 0; r < 4; r++) { m[r] = -1e30f; lsum[r] = 0.f; }

  const float* lbh = lb + (size_t)kvh * T_SEQ;
  const unsigned short* Kh = Kb + kvh * DH;
  const unsigned short* Vh = Vt + (size_t)kvh * DH * T_SEQ;
  const int ntiles = (qb + 79) >> 6;    // ceil((qb+16)/64)

  const int ir[4] = {qb + lg * 4, qb + lg * 4 + 1, qb + lg * 4 + 2, qb + lg * 4 + 3};
  const float fi[4] = {(float)ir[0], (float)ir[1], (float)ir[2], (float)ir[3]};

  // preload K fragments for first (diagonal) tile
  bf16x8 kf[16];
  {
    const int kb0 = (ntiles - 1) * 64;
#pragma unroll
    for (int nf = 0; nf < 4; nf++) {
      const unsigned short* kp = Kh + (size_t)(kb0 + nf * 16 + lr) * 1024 + lg * 8;
#pragma unroll
      for (int kc = 0; kc < 4; kc++) kf[nf * 4 + kc] = *(const bf16x8*)(kp + kc * 32);
    }
  }

  for (int kt = ntiles - 1; kt >= 0; --kt) {
    const int kb = kt * 64;
    // ---- QK^T (uses current kf) ----
    f32x4 sfr[4];
#pragma unroll
    for (int nf = 0; nf < 4; nf++) {
      f32x4 a = (f32x4){0.f, 0.f, 0.f, 0.f};
#pragma unroll
      for (int kc = 0; kc < 4; kc++)
        a = __builtin_amdgcn_mfma_f32_16x16x32_bf16(qf[kc], kf[nf * 4 + kc], a, 0, 0, 0);
      sfr[nf] = a;
    }
    // ---- prefetch next (older) K tile into kf; latency hides under softmax+PV ----
    {
      const int kbn = (kt > 0) ? kb - 64 : 0;
#pragma unroll
      for (int nf = 0; nf < 4; nf++) {
        const unsigned short* kp = Kh + (size_t)(kbn + nf * 16 + lr) * 1024 + lg * 8;
#pragma unroll
        for (int kc = 0; kc < 4; kc++) kf[nf * 4 + kc] = *(const bf16x8*)(kp + kc * 32);
      }
    }
    // ---- bias + (diagonal-tile-only) causal mask + tile row-max ----
    float tm[4];
#pragma unroll
    for (int r = 0; r < 4; r++) tm[r] = -1e30f;
    const int last = (kt == ntiles - 1);
#pragma unroll
    for (int nf = 0; nf < 4; nf++) {
      const int j = kb + nf * 16 + lr;
      const float lbv = lbh[j];
      const float fj = (float)j;
#pragma unroll
      for (int r = 0; r < 4; r++) {
        float sv = sfr[nf][r] + lbv * (fi[r] - fj);
        if (last) sv = (j <= ir[r]) ? sv : -1e30f;
        sfr[nf][r] = sv;
        tm[r] = fmaxf(tm[r], sv);
      }
    }
#pragma unroll
    for (int off = 8; off >= 1; off >>= 1)
#pragma unroll
      for (int r = 0; r < 4; r++) tm[r] = fmaxf(tm[r], __shfl_xor(tm[r], off));
    // ---- online softmax: skip rescale when running max unchanged (decay => common) ----
    float nm[4];
#pragma unroll
    for (int r = 0; r < 4; r++) nm[r] = fmaxf(m[r], tm[r]);
    const int upd = (nm[0] > m[0]) | (nm[1] > m[1]) | (nm[2] > m[2]) | (nm[3] > m[3]);
    if (__any(upd)) {
#pragma unroll
      for (int r = 0; r < 4; r++) {
        const float corr = exp2f(m[r] - nm[r]);
        m[r] = nm[r];
        lsum[r] *= corr;
#pragma unroll
        for (int nc = 0; nc < 8; nc++) o[nc][r] *= corr;
      }
    }
    float rs[4];
#pragma unroll
    for (int r = 0; r < 4; r++) rs[r] = 0.f;
#pragma unroll
    for (int nf = 0; nf < 4; nf++)
#pragma unroll
      for (int r = 0; r < 4; r++) {
        const float p = exp2f(sfr[nf][r] - m[r]);
        sfr[nf][r] = p;
        rs[r] += p;
      }
#pragma unroll
    for (int off = 8; off >= 1; off >>= 1)
#pragma unroll
      for (int r = 0; r < 4; r++) rs[r] += __shfl_xor(rs[r], off);
#pragma unroll
    for (int r = 0; r < 4; r++) lsum[r] += rs[r];
    // ---- P -> LDS (per-wave private; same-wave in-order LDS pipe, no barrier) ----
#pragma unroll
    for (int nf = 0; nf < 4; nf++)
#pragma unroll
      for (int r = 0; r < 4; r++)
        myp[(lg * 4 + r) * 72 + nf * 16 + lr] = f2bf(sfr[nf][r]);
    const bf16x8 pa0 = *(const bf16x8*)&myp[lr * 72 + lg * 8];
    const bf16x8 pa1 = *(const bf16x8*)&myp[lr * 72 + 32 + lg * 8];
    // ---- PV ----
#pragma unroll
    for (int nc = 0; nc < 8; nc++) {
      const unsigned short* vp = Vh + (size_t)(nc * 16 + lr) * T_SEQ + kb + lg * 8;
      const bf16x8 v0 = *(const bf16x8*)vp;
      const bf16x8 v1 = *(const bf16x8*)(vp + 32);
      o[nc] = __builtin_amdgcn_mfma_f32_16x16x32_bf16(pa0, v0, o[nc], 0, 0, 0);
      o[nc] = __builtin_amdgcn_mfma_f32_16x16x32_bf16(pa1, v1, o[nc], 0, 0, 0);
    }
  }
  float inv[4];
#pragma unroll
  for (int r = 0; r < 4; r++) inv[r] = 1.f / lsum[r];
#pragma unroll
  for (int nc = 0; nc < 8; nc++)
#pragma unroll
    for (int r = 0; r < 4; r++)
      O[(size_t)(qb + lg * 4 + r) * 2048 + h * DH + nc * 16 + lr] = f2bf(o[nc][r] * inv[r]);
}

extern "C" void kernel_launch(void* const* d_in, const int* in_sizes, int n_in,
                              void* d_out, int out_size, void* d_ws, size_t ws_size,
                              hipStream_t stream) {
  const float* hidden = (const float*)d_in[0];
  const float* Wq     = (const float*)d_in[1];
  const float* Wk     = (const float*)d_in[2];
  const float* Wv     = (const float*)d_in[3];
  const float* Wo     = (const float*)d_in[4];
  const float* qw     = (const float*)d_in[5];
  const float* kw     = (const float*)d_in[6];
  const float* gw     = (const float*)d_in[7];
  const float* gb     = (const float*)d_in[8];
  const float* cosT   = (const float*)d_in[9];
  const float* sinT   = (const float*)d_in[10];

  char* ws = (char*)d_ws;
  const size_t MB = (size_t)1 << 20;
  unsigned short* hbf   = (unsigned short*)(ws);              // 8 MB  bf16 hidden [2048][2048]
  unsigned short* BtQKV = (unsigned short*)(ws + 8 * MB);     // 16 MB bf16 [4096][2048] (Wq^T|Wk^T|Wv^T)
  unsigned short* WoT   = (unsigned short*)(ws + 24 * MB);    // 8 MB  bf16 [2048][2048] Wo^T
  float*          qkv   = (float*)(ws + 32 * MB);             // 32 MB fp32 [2048][4096]
  unsigned short* Qb    = (unsigned short*)(ws + 64 * MB);    // 8 MB  bf16 [2048][2048]
  unsigned short* Kbuf  = (unsigned short*)(ws + 72 * MB);    // 4 MB  bf16 [2048][1024]
  unsigned short* Vt    = (unsigned short*)(ws + 76 * MB);    // 4 MB  bf16 [8][128][2048]
  unsigned short* AO    = (unsigned short*)(ws + 80 * MB);    // 8 MB  bf16 [2048][2048]
  float*          lbuf  = (float*)(ws + 88 * MB);             // 64 KB fp32 [8][2048] (log2 beta)

  k_cvt<<<4096, 256, 0, stream>>>(hidden, hbf, (HID * T_SEQ) / 4);
  k_transpose_cvt<<<dim3(32, 32), 256, 0, stream>>>(Wq, BtQKV, 2048, 2048);
  k_transpose_cvt<<<dim3(32, 16), 256, 0, stream>>>(Wk, BtQKV + (size_t)2048 * 2048, 1024, 2048);
  k_transpose_cvt<<<dim3(32, 16), 256, 0, stream>>>(Wv, BtQKV + (size_t)3072 * 2048, 1024, 2048);
  k_transpose_cvt<<<dim3(32, 32), 256, 0, stream>>>(Wo, WoT, 2048, 2048);
  k_gate<<<512, 256, 0, stream>>>(hidden, gw, gb, lbuf);
  k_gemm_bt<<<dim3(16, 32), 256, 0, stream>>>(hbf, BtQKV, qkv, 2048, 4096);
  k_norm_rope<<<2048, 256, 0, stream>>>(qkv, qw, kw, cosT, sinT, Qb, Kbuf);
  k_transpose_cvt<<<dim3(32, 16), 256, 0, stream>>>(qkv + 3072, Vt, 4096, 2048);
  k_attn<<<dim3(512), 256, 0, stream>>>(Qb, Kbuf, Vt, lbuf, AO);
  k_gemm_bt<<<dim3(16, 16), 256, 0, stream>>>(AO, WoT, (float*)d_out, 2048, 2048);
}

// Round 3
// 207.288 us; speedup vs baseline: 1.8816x; 1.8573x over previous
//
#include <hip/hip_runtime.h>

// ---- constants (problem sizes fixed by reference) ----
#define T_SEQ 2048
#define HID   2048
#define HQ    16
#define HKV   8
#define DH    128
#define NQKV  4096   // HQ*DH + 2*HKV*DH

#define QSCALE (0.08838834764831845f * 1.4426950408889634f)  // 1/sqrt(128) * log2(e)

typedef __attribute__((ext_vector_type(8))) __bf16 bf16x8;
typedef __attribute__((ext_vector_type(4))) float f32x4;
typedef __attribute__((ext_vector_type(8))) unsigned short ushort8;

__device__ __forceinline__ unsigned short f2bf(float f) {
  unsigned u = __builtin_bit_cast(unsigned, f);
  u += 0x7fffu + ((u >> 16) & 1u);
  return (unsigned short)(u >> 16);
}

__device__ __forceinline__ void gload_lds16(const void* g, void* l) {
  __builtin_amdgcn_global_load_lds((const __attribute__((address_space(1))) void*)g,
                                   (__attribute__((address_space(3))) void*)l, 16, 0, 0);
}

// ---- fp32 -> bf16 copy-convert (row-major preserved) ----
__global__ __launch_bounds__(256) void k_cvt(const float* __restrict__ in,
                                             unsigned short* __restrict__ out, int n4) {
  int i = blockIdx.x * 256 + threadIdx.x;
  if (i >= n4) return;
  float4 v = ((const float4*)in)[i];
  unsigned long long pk = (unsigned long long)f2bf(v.x)
                        | ((unsigned long long)f2bf(v.y) << 16)
                        | ((unsigned long long)f2bf(v.z) << 32)
                        | ((unsigned long long)f2bf(v.w) << 48);
  ((unsigned long long*)out)[i] = pk;
}

// ---- fp32 [R][C] (row stride ldin) -> bf16 [C][R] (row stride ldout); 64x64 tiles ----
__global__ __launch_bounds__(256) void k_transpose_cvt(const float* __restrict__ in,
                                                       unsigned short* __restrict__ out,
                                                       int ldin, int ldout) {
  __shared__ float tile[64][65];
  const int r0 = blockIdx.x * 64;
  const int c0 = blockIdx.y * 64;
  const int tid = threadIdx.x;
  {
    const int row = tid >> 4;          // 0..15
    const int cf  = (tid & 15) * 4;    // float4 col
#pragma unroll
    for (int k = 0; k < 4; k++) {
      const int r = row + k * 16;
      float4 v = *(const float4*)(in + (size_t)(r0 + r) * ldin + c0 + cf);
      tile[r][cf + 0] = v.x; tile[r][cf + 1] = v.y;
      tile[r][cf + 2] = v.z; tile[r][cf + 3] = v.w;
    }
  }
  __syncthreads();
  {
    const int c    = tid >> 3;         // 0..31
    const int rseg = (tid & 7) * 8;    // 8 elems
#pragma unroll
    for (int k = 0; k < 2; k++) {
      const int cc = c + k * 32;
      ushort8 ov;
#pragma unroll
      for (int e = 0; e < 8; e++) ov[e] = f2bf(tile[rseg + e][cc]);
      *(ushort8*)(out + (size_t)(c0 + cc) * ldout + r0 + rseg) = ov;
    }
  }
}

// ---- gate: lb[h][t] = log2(clip(sigmoid(hidden[t] . gw[:,h] + gb[h]), 1e-8)) ----
__global__ __launch_bounds__(256) void k_gate(const float* __restrict__ hid,
                                              const float* __restrict__ gw,
                                              const float* __restrict__ gb,
                                              float* __restrict__ lb) {
  const int t = blockIdx.x * 4 + (threadIdx.x >> 6);
  const int lane = threadIdx.x & 63;
  float acc[8];
#pragma unroll
  for (int h = 0; h < 8; h++) acc[h] = 0.f;
  const float* hrow = hid + (size_t)t * HID;
  for (int i = lane; i < HID; i += 64) {
    const float hv = hrow[i];
    const float4 a = *(const float4*)(gw + (size_t)i * 8);
    const float4 b = *(const float4*)(gw + (size_t)i * 8 + 4);
    acc[0] += hv * a.x; acc[1] += hv * a.y; acc[2] += hv * a.z; acc[3] += hv * a.w;
    acc[4] += hv * b.x; acc[5] += hv * b.y; acc[6] += hv * b.z; acc[7] += hv * b.w;
  }
#pragma unroll
  for (int off = 32; off >= 1; off >>= 1)
#pragma unroll
    for (int h = 0; h < 8; h++) acc[h] += __shfl_xor(acc[h], off);
  if (lane == 0) {
#pragma unroll
    for (int h = 0; h < 8; h++) {
      const float x = acc[h] + gb[h];
      const float beta = 1.f / (1.f + __expf(-x));
      lb[(size_t)h * T_SEQ + t] = log2f(fmaxf(beta, 1e-8f));   // log2 domain
    }
  }
}

// ---- per-head max of lb (for rigorous attention early-exit bound) ----
__global__ __launch_bounds__(256) void k_lbmax(const float* __restrict__ lb,
                                               float* __restrict__ lbm) {
  const int h = blockIdx.x;
  float v = -1e30f;
  for (int i = threadIdx.x; i < T_SEQ; i += 256) v = fmaxf(v, lb[(size_t)h * T_SEQ + i]);
#pragma unroll
  for (int o = 32; o >= 1; o >>= 1) v = fmaxf(v, __shfl_xor(v, o));
  __shared__ float s[4];
  if ((threadIdx.x & 63) == 0) s[threadIdx.x >> 6] = v;
  __syncthreads();
  if (threadIdx.x == 0) lbm[h] = fmaxf(fmaxf(s[0], s[1]), fmaxf(s[2], s[3]));
}

// ---- per-head RMSNorm + RoPE; qkv fp32 [T][4096] -> Qb bf16 [T][2048] (pre-scaled), Kb bf16 [T][1024] ----
__global__ __launch_bounds__(256) void k_norm_rope(const float* __restrict__ qkv,
                                                   const float* __restrict__ qw,
                                                   const float* __restrict__ kw,
                                                   const float* __restrict__ cosT,
                                                   const float* __restrict__ sinT,
                                                   unsigned short* __restrict__ Qb,
                                                   unsigned short* __restrict__ Kb) {
  const int t = blockIdx.x;
  const int wid = threadIdx.x >> 6, lane = threadIdx.x & 63;
  const float* row = qkv + (size_t)t * NQKV;
  const float c1 = cosT[t * DH + lane],      s1 = sinT[t * DH + lane];
  const float c2 = cosT[t * DH + 64 + lane], s2 = sinT[t * DH + 64 + lane];
  for (int hh = wid; hh < 24; hh += 4) {
    const int off = hh * DH;   // q heads: cols 0..2047 ; k heads: cols 2048..3071
    const float* x = row + off;
    const float x1 = x[lane], x2 = x[lane + 64];
    float ss = x1 * x1 + x2 * x2;
#pragma unroll
    for (int o = 32; o >= 1; o >>= 1) ss += __shfl_xor(ss, o);
    const float rinv = rsqrtf(ss * (1.f / DH) + 1e-6f);
    const float* wv = (hh < 16) ? qw : kw;
    const float y1 = x1 * rinv * wv[lane];
    const float y2 = x2 * rinv * wv[lane + 64];
    float o1 = y1 * c1 - y2 * s1;
    float o2 = y2 * c2 + y1 * s2;
    if (hh < 16) {
      o1 *= QSCALE; o2 *= QSCALE;   // fold attn scale + log2e into Q
      Qb[(size_t)t * 2048 + hh * DH + lane]      = f2bf(o1);
      Qb[(size_t)t * 2048 + hh * DH + lane + 64] = f2bf(o2);
    } else {
      Kb[(size_t)t * 1024 + (hh - 16) * DH + lane]      = f2bf(o1);
      Kb[(size_t)t * 1024 + (hh - 16) * DH + lane + 64] = f2bf(o2);
    }
  }
}

// ---- bf16 GEMM: C[M][N] fp32 = A[M][K] * Bt[N][K]^T ; 128x128 tile, BK=32, 4 waves ----
__global__ __launch_bounds__(256) void k_gemm_bt(const unsigned short* __restrict__ A,
                                                 const unsigned short* __restrict__ Bt,
                                                 float* __restrict__ C, int K, int N) {
  __shared__ unsigned short lA[128 * 32];
  __shared__ unsigned short lB[128 * 32];
  const int tid = threadIdx.x;
  const int wid = tid >> 6, lane = tid & 63;
  const int lr = lane & 15, lg = lane >> 4;
  const int wr = wid >> 1, wc = wid & 1;
  const size_t tile_m = (size_t)blockIdx.x * 128, tile_n = (size_t)blockIdx.y * 128;

  f32x4 acc[4][4];
#pragma unroll
  for (int i = 0; i < 4; i++)
#pragma unroll
    for (int j = 0; j < 4; j++) acc[i][j] = (f32x4){0.f, 0.f, 0.f, 0.f};

  const int sr0 = wid * 32 + (lane >> 2);
  const int sc  = (lane & 3) * 16;  // bytes
  const char* gA0 = (const char*)A  + (tile_m + sr0) * (size_t)K * 2 + sc;
  const char* gA1 = gA0 + (size_t)16 * K * 2;
  const char* gB0 = (const char*)Bt + (tile_n + sr0) * (size_t)K * 2 + sc;
  const char* gB1 = gB0 + (size_t)16 * K * 2;
  char* lA0 = (char*)lA + wid * 2048;
  char* lA1 = lA0 + 1024;
  char* lB0 = (char*)lB + wid * 2048;
  char* lB1 = lB0 + 1024;

  for (int kb = 0; kb < K * 2; kb += 64) {  // kb in bytes
    gload_lds16(gA0 + kb, lA0);
    gload_lds16(gA1 + kb, lA1);
    gload_lds16(gB0 + kb, lB0);
    gload_lds16(gB1 + kb, lB1);
    __syncthreads();
    bf16x8 af[4], bfr[4];
#pragma unroll
    for (int mi = 0; mi < 4; mi++)
      af[mi] = *(const bf16x8*)&lA[(wr * 64 + mi * 16 + lr) * 32 + lg * 8];
#pragma unroll
    for (int ni = 0; ni < 4; ni++)
      bfr[ni] = *(const bf16x8*)&lB[(wc * 64 + ni * 16 + lr) * 32 + lg * 8];
#pragma unroll
    for (int mi = 0; mi < 4; mi++)
#pragma unroll
      for (int ni = 0; ni < 4; ni++)
        acc[mi][ni] = __builtin_amdgcn_mfma_f32_16x16x32_bf16(af[mi], bfr[ni], acc[mi][ni], 0, 0, 0);
    __syncthreads();
  }
#pragma unroll
  for (int mi = 0; mi < 4; mi++)
#pragma unroll
    for (int ni = 0; ni < 4; ni++)
#pragma unroll
      for (int r = 0; r < 4; r++)
        C[(tile_m + wr * 64 + mi * 16 + lg * 4 + r) * (size_t)N + tile_n + wc * 64 + ni * 16 + lr] =
            acc[mi][ni][r];
}

// ---- flash attention: block = (head, 64 q-rows), 4 waves; K/V staged to LDS via
//      global_load_lds (double-buffered, counted vmcnt, XOR-swizzled via pre-swizzled
//      global source); reverse iteration + rigorous decay early-exit ----
__global__ __launch_bounds__(256, 2) void k_attn(const unsigned short* __restrict__ Q,
                                                 const unsigned short* __restrict__ Kb,
                                                 const unsigned short* __restrict__ Vt,
                                                 const float* __restrict__ lb,
                                                 const float* __restrict__ lbmax,
                                                 unsigned short* __restrict__ O) {
  const int tid = threadIdx.x;
  const int wid = tid >> 6, lane = tid & 63;
  const int lr = lane & 15, lg = lane >> 4;
  const int h = blockIdx.x >> 5;      // q head
  const int qblk = blockIdx.x & 31;   // 64-row block
  const int kvh = h >> 1;             // G = 2
  const int qb = qblk * 64 + wid * 16;

  __shared__ __align__(16) unsigned short lK[2][64 * 128];   // [row][128 shorts], swizzled chunks
  __shared__ __align__(16) unsigned short lV[2][128 * 64];   // [d-row][64 shorts], swizzled chunks
  __shared__ __align__(16) unsigned short plds[4][16 * 72];
  __shared__ int exitflag[4];

  const float* lbh = lb + (size_t)kvh * T_SEQ;
  const unsigned short* Kh = Kb + kvh * DH;
  const unsigned short* Vh = Vt + (size_t)kvh * DH * T_SEQ;
  const float lbmx = lbmax[kvh];
  unsigned short* myp = plds[wid];

  // Q fragments (Q pre-scaled by 1/sqrt(D)*log2e)
  bf16x8 qf[4];
  {
    const unsigned short* Qp = Q + (size_t)(qb + lr) * 2048 + h * DH + lg * 8;
#pragma unroll
    for (int kc = 0; kc < 4; kc++) qf[kc] = *(const bf16x8*)(Qp + kc * 32);
  }

  f32x4 o[8];
#pragma unroll
  for (int nc = 0; nc < 8; nc++) o[nc] = (f32x4){0.f, 0.f, 0.f, 0.f};
  float m[4], lsum[4];
#pragma unroll
  for (int r = 0; r < 4; r++) { m[r] = -1e30f; lsum[r] = 0.f; }

  const int ir[4] = {qb + lg * 4, qb + lg * 4 + 1, qb + lg * 4 + 2, qb + lg * 4 + 3};
  const float fi[4] = {(float)ir[0], (float)ir[1], (float)ir[2], (float)ir[3]};

  // stage one 64-wide K/V tile into buffer buf (8 DMA ops per wave; swizzled source)
  auto stage = [&](int kb, int buf) {
#pragma unroll
    for (int q = 0; q < 4; q++) {
      const int t = wid * 4 + q;
      {  // K rows 4t..4t+3 (256B rows, 16 chunks)
        const int r = 4 * t + (lane >> 4);
        const int j = (lane & 15) ^ (r & 7);
        gload_lds16(Kh + (size_t)(kb + r) * 1024 + j * 8, &lK[buf][t * 512]);
      }
      {  // V rows 8t..8t+3.. (128B rows, 8 chunks)
        const int r = 8 * t + (lane >> 3);
        const int j = (lane & 7) ^ (r & 7);
        gload_lds16(Vh + (size_t)r * 2048 + kb + j * 8, &lV[buf][t * 512]);
      }
    }
  };

  const int nt = qblk + 1;
  int cur = 0;
  stage((nt - 1) * 64, 0);
  float lbv = lbh[(nt - 1) * 64 + lane];
  float lbn = 0.f;

  for (int kt = nt - 1; kt >= 0; --kt) {
    const int kb = kt * 64;
    if (kt > 0) {
      stage(kb - 64, cur ^ 1);
      lbn = lbh[kb - 64 + lane];
      asm volatile("s_waitcnt vmcnt(9)" ::: "memory");   // prev tile's 8 DMA + its lb done
    } else {
      asm volatile("s_waitcnt vmcnt(0)" ::: "memory");
    }
    __syncthreads();
    // ---- QK^T from lK[cur] ----
    f32x4 sfr[4];
#pragma unroll
    for (int nf = 0; nf < 4; nf++) {
      const int rr = nf * 16 + lr;
      const unsigned short* kbase = &lK[cur][rr * 128];
      f32x4 a = (f32x4){0.f, 0.f, 0.f, 0.f};
#pragma unroll
      for (int kc = 0; kc < 4; kc++) {
        const bf16x8 kf = *(const bf16x8*)&kbase[((kc * 4 + lg) ^ (rr & 7)) * 8];
        a = __builtin_amdgcn_mfma_f32_16x16x32_bf16(qf[kc], kf, a, 0, 0, 0);
      }
      sfr[nf] = a;
    }
    // ---- bias + (diagonal-tile-only) causal mask + tile row-max ----
    float lbj[4];
#pragma unroll
    for (int nf = 0; nf < 4; nf++) lbj[nf] = __shfl(lbv, nf * 16 + lr);
    float tm[4];
#pragma unroll
    for (int r = 0; r < 4; r++) tm[r] = -1e30f;
    const int last = (kt == nt - 1);
#pragma unroll
    for (int nf = 0; nf < 4; nf++) {
      const int j = kb + nf * 16 + lr;
      const float fj = (float)j;
#pragma unroll
      for (int r = 0; r < 4; r++) {
        float sv = sfr[nf][r] + lbj[nf] * (fi[r] - fj);
        if (last) sv = (j <= ir[r]) ? sv : -1e30f;
        sfr[nf][r] = sv;
        tm[r] = fmaxf(tm[r], sv);
      }
    }
#pragma unroll
    for (int off = 8; off >= 1; off >>= 1)
#pragma unroll
      for (int r = 0; r < 4; r++) tm[r] = fmaxf(tm[r], __shfl_xor(tm[r], off));
    // ---- online softmax; skip rescale when running max unchanged ----
    float nm[4];
#pragma unroll
    for (int r = 0; r < 4; r++) nm[r] = fmaxf(m[r], tm[r]);
    const int upd = (nm[0] > m[0]) | (nm[1] > m[1]) | (nm[2] > m[2]) | (nm[3] > m[3]);
    if (__any(upd)) {
#pragma unroll
      for (int r = 0; r < 4; r++) {
        const float corr = exp2f(m[r] - nm[r]);
        m[r] = nm[r];
        lsum[r] *= corr;
#pragma unroll
        for (int nc = 0; nc < 8; nc++) o[nc][r] *= corr;
      }
    }
    float rs[4];
#pragma unroll
    for (int r = 0; r < 4; r++) rs[r] = 0.f;
#pragma unroll
    for (int nf = 0; nf < 4; nf++)
#pragma unroll
      for (int r = 0; r < 4; r++) {
        const float p = exp2f(sfr[nf][r] - m[r]);
        sfr[nf][r] = p;
        rs[r] += p;
      }
#pragma unroll
    for (int off = 8; off >= 1; off >>= 1)
#pragma unroll
      for (int r = 0; r < 4; r++) rs[r] += __shfl_xor(rs[r], off);
#pragma unroll
    for (int r = 0; r < 4; r++) lsum[r] += rs[r];
    // ---- P -> per-wave LDS, read back as A-frag ----
#pragma unroll
    for (int nf = 0; nf < 4; nf++)
#pragma unroll
      for (int r = 0; r < 4; r++)
        myp[(lg * 4 + r) * 72 + nf * 16 + lr] = f2bf(sfr[nf][r]);
    const bf16x8 pa0 = *(const bf16x8*)&myp[lr * 72 + lg * 8];
    const bf16x8 pa1 = *(const bf16x8*)&myp[lr * 72 + 32 + lg * 8];
    // ---- PV from lV[cur] ----
#pragma unroll
    for (int nc = 0; nc < 8; nc++) {
      const int rr = nc * 16 + lr;
      const unsigned short* vbase = &lV[cur][rr * 64];
      const bf16x8 v0 = *(const bf16x8*)&vbase[(lg ^ (rr & 7)) * 8];
      const bf16x8 v1 = *(const bf16x8*)&vbase[((4 + lg) ^ (rr & 7)) * 8];
      o[nc] = __builtin_amdgcn_mfma_f32_16x16x32_bf16(pa0, v0, o[nc], 0, 0, 0);
      o[nc] = __builtin_amdgcn_mfma_f32_16x16x32_bf16(pa1, v1, o[nc], 0, 0, 0);
    }
    // ---- rigorous early exit: remaining score <= 16.5 + lbmax*(i-kb+1) ----
    int ok = 1;
    const float fkb = (float)kb;
#pragma unroll
    for (int r = 0; r < 4; r++)
      ok &= (16.5f + lbmx * (fi[r] - fkb + 1.0f) < m[r] - 25.0f) ? 1 : 0;
    const int wall = __all(ok) ? 1 : 0;
    if (lane == 0) exitflag[wid] = wall;
    __syncthreads();   // also: all waves done reading buf[cur^1]'s predecessor
    if (exitflag[0] && exitflag[1] && exitflag[2] && exitflag[3]) break;
    lbv = lbn;
    cur ^= 1;
  }
  asm volatile("s_waitcnt vmcnt(0)" ::: "memory");  // drain stray prefetch before exit
  float inv[4];
#pragma unroll
  for (int r = 0; r < 4; r++) inv[r] = 1.f / lsum[r];
#pragma unroll
  for (int nc = 0; nc < 8; nc++)
#pragma unroll
    for (int r = 0; r < 4; r++)
      O[(size_t)(qb + lg * 4 + r) * 2048 + h * DH + nc * 16 + lr] = f2bf(o[nc][r] * inv[r]);
}

extern "C" void kernel_launch(void* const* d_in, const int* in_sizes, int n_in,
                              void* d_out, int out_size, void* d_ws, size_t ws_size,
                              hipStream_t stream) {
  const float* hidden = (const float*)d_in[0];
  const float* Wq     = (const float*)d_in[1];
  const float* Wk     = (const float*)d_in[2];
  const float* Wv     = (const float*)d_in[3];
  const float* Wo     = (const float*)d_in[4];
  const float* qw     = (const float*)d_in[5];
  const float* kw     = (const float*)d_in[6];
  const float* gw     = (const float*)d_in[7];
  const float* gb     = (const float*)d_in[8];
  const float* cosT   = (const float*)d_in[9];
  const float* sinT   = (const float*)d_in[10];

  char* ws = (char*)d_ws;
  const size_t MB = (size_t)1 << 20;
  unsigned short* hbf   = (unsigned short*)(ws);              // 8 MB  bf16 hidden [2048][2048]
  unsigned short* BtQKV = (unsigned short*)(ws + 8 * MB);     // 16 MB bf16 [4096][2048]
  unsigned short* WoT   = (unsigned short*)(ws + 24 * MB);    // 8 MB  bf16 [2048][2048] Wo^T
  float*          qkv   = (float*)(ws + 32 * MB);             // 32 MB fp32 [2048][4096]
  unsigned short* Qb    = (unsigned short*)(ws + 64 * MB);    // 8 MB  bf16 [2048][2048]
  unsigned short* Kbuf  = (unsigned short*)(ws + 72 * MB);    // 4 MB  bf16 [2048][1024]
  unsigned short* Vt    = (unsigned short*)(ws + 76 * MB);    // 4 MB  bf16 [8][128][2048]
  unsigned short* AO    = (unsigned short*)(ws + 80 * MB);    // 8 MB  bf16 [2048][2048]
  float*          lbuf  = (float*)(ws + 88 * MB);             // 64 KB fp32 [8][2048] (log2 beta)
  float*          lbm   = (float*)(ws + 88 * MB + 65536);     // 32 B  fp32 [8]

  k_cvt<<<4096, 256, 0, stream>>>(hidden, hbf, (HID * T_SEQ) / 4);
  k_transpose_cvt<<<dim3(32, 32), 256, 0, stream>>>(Wq, BtQKV, 2048, 2048);
  k_transpose_cvt<<<dim3(32, 16), 256, 0, stream>>>(Wk, BtQKV + (size_t)2048 * 2048, 1024, 2048);
  k_transpose_cvt<<<dim3(32, 16), 256, 0, stream>>>(Wv, BtQKV + (size_t)3072 * 2048, 1024, 2048);
  k_transpose_cvt<<<dim3(32, 32), 256, 0, stream>>>(Wo, WoT, 2048, 2048);
  k_gate<<<512, 256, 0, stream>>>(hidden, gw, gb, lbuf);
  k_lbmax<<<8, 256, 0, stream>>>(lbuf, lbm);
  k_gemm_bt<<<dim3(16, 32), 256, 0, stream>>>(hbf, BtQKV, qkv, 2048, 4096);
  k_norm_rope<<<2048, 256, 0, stream>>>(qkv, qw, kw, cosT, sinT, Qb, Kbuf);
  k_transpose_cvt<<<dim3(32, 16), 256, 0, stream>>>(qkv + 3072, Vt, 4096, 2048);
  k_attn<<<dim3(512), 256, 0, stream>>>(Qb, Kbuf, Vt, lbuf, lbm, AO);
  k_gemm_bt<<<dim3(16, 16), 256, 0, stream>>>(AO, WoT, (float*)d_out, 2048, 2048);
}

// Round 4
// 176.910 us; speedup vs baseline: 2.2047x; 1.1717x over previous
//
#include <hip/hip_runtime.h>

// ---- constants (problem sizes fixed by reference) ----
#define T_SEQ 2048
#define HID   2048
#define HQ    16
#define HKV   8
#define DH    128
#define NQKV  4096   // HQ*DH + 2*HKV*DH

#define QSCALE (0.08838834764831845f * 1.4426950408889634f)  // 1/sqrt(128) * log2(e)

typedef __attribute__((ext_vector_type(8))) __bf16 bf16x8;
typedef __attribute__((ext_vector_type(4))) float f32x4;
typedef __attribute__((ext_vector_type(8))) unsigned short ushort8;

__device__ __forceinline__ unsigned short f2bf(float f) {
  unsigned u = __builtin_bit_cast(unsigned, f);
  u += 0x7fffu + ((u >> 16) & 1u);
  return (unsigned short)(u >> 16);
}

__device__ __forceinline__ void gload_lds16(const void* g, void* l) {
  __builtin_amdgcn_global_load_lds((const __attribute__((address_space(1))) void*)g,
                                   (__attribute__((address_space(3))) void*)l, 16, 0, 0);
}

// ---- fp32 -> bf16 copy-convert (row-major preserved) ----
__global__ __launch_bounds__(256) void k_cvt(const float* __restrict__ in,
                                             unsigned short* __restrict__ out, int n4) {
  int i = blockIdx.x * 256 + threadIdx.x;
  if (i >= n4) return;
  float4 v = ((const float4*)in)[i];
  unsigned long long pk = (unsigned long long)f2bf(v.x)
                        | ((unsigned long long)f2bf(v.y) << 16)
                        | ((unsigned long long)f2bf(v.z) << 32)
                        | ((unsigned long long)f2bf(v.w) << 48);
  ((unsigned long long*)out)[i] = pk;
}

// ---- fp32 [R][C] (row stride ldin) -> bf16 [C][R] (row stride ldout); 64x64 tiles ----
__global__ __launch_bounds__(256) void k_transpose_cvt(const float* __restrict__ in,
                                                       unsigned short* __restrict__ out,
                                                       int ldin, int ldout) {
  __shared__ float tile[64][65];
  const int r0 = blockIdx.x * 64;
  const int c0 = blockIdx.y * 64;
  const int tid = threadIdx.x;
  {
    const int row = tid >> 4;          // 0..15
    const int cf  = (tid & 15) * 4;    // float4 col
#pragma unroll
    for (int k = 0; k < 4; k++) {
      const int r = row + k * 16;
      float4 v = *(const float4*)(in + (size_t)(r0 + r) * ldin + c0 + cf);
      tile[r][cf + 0] = v.x; tile[r][cf + 1] = v.y;
      tile[r][cf + 2] = v.z; tile[r][cf + 3] = v.w;
    }
  }
  __syncthreads();
  {
    const int c    = tid >> 3;         // 0..31
    const int rseg = (tid & 7) * 8;    // 8 elems
#pragma unroll
    for (int k = 0; k < 2; k++) {
      const int cc = c + k * 32;
      ushort8 ov;
#pragma unroll
      for (int e = 0; e < 8; e++) ov[e] = f2bf(tile[rseg + e][cc]);
      *(ushort8*)(out + (size_t)(c0 + cc) * ldout + r0 + rseg) = ov;
    }
  }
}

// ---- gate: lb[h][t] = log2(clip(sigmoid(hidden[t] . gw[:,h] + gb[h]), 1e-8)) ----
__global__ __launch_bounds__(256) void k_gate(const float* __restrict__ hid,
                                              const float* __restrict__ gw,
                                              const float* __restrict__ gb,
                                              float* __restrict__ lb) {
  const int t = blockIdx.x * 4 + (threadIdx.x >> 6);
  const int lane = threadIdx.x & 63;
  float acc[8];
#pragma unroll
  for (int h = 0; h < 8; h++) acc[h] = 0.f;
  const float* hrow = hid + (size_t)t * HID;
  for (int i = lane; i < HID; i += 64) {
    const float hv = hrow[i];
    const float4 a = *(const float4*)(gw + (size_t)i * 8);
    const float4 b = *(const float4*)(gw + (size_t)i * 8 + 4);
    acc[0] += hv * a.x; acc[1] += hv * a.y; acc[2] += hv * a.z; acc[3] += hv * a.w;
    acc[4] += hv * b.x; acc[5] += hv * b.y; acc[6] += hv * b.z; acc[7] += hv * b.w;
  }
#pragma unroll
  for (int off = 32; off >= 1; off >>= 1)
#pragma unroll
    for (int h = 0; h < 8; h++) acc[h] += __shfl_xor(acc[h], off);
  if (lane == 0) {
#pragma unroll
    for (int h = 0; h < 8; h++) {
      const float x = acc[h] + gb[h];
      const float beta = 1.f / (1.f + __expf(-x));
      lb[(size_t)h * T_SEQ + t] = log2f(fmaxf(beta, 1e-8f));   // log2 domain
    }
  }
}

// ---- per-head max of lb (for rigorous attention early-exit bound) ----
__global__ __launch_bounds__(256) void k_lbmax(const float* __restrict__ lb,
                                               float* __restrict__ lbm) {
  const int h = blockIdx.x;
  float v = -1e30f;
  for (int i = threadIdx.x; i < T_SEQ; i += 256) v = fmaxf(v, lb[(size_t)h * T_SEQ + i]);
#pragma unroll
  for (int o = 32; o >= 1; o >>= 1) v = fmaxf(v, __shfl_xor(v, o));
  __shared__ float s[4];
  if ((threadIdx.x & 63) == 0) s[threadIdx.x >> 6] = v;
  __syncthreads();
  if (threadIdx.x == 0) lbm[h] = fmaxf(fmaxf(s[0], s[1]), fmaxf(s[2], s[3]));
}

// ---- per-head RMSNorm + RoPE; qkv fp32 [T][4096] -> Qb bf16 [T][2048] (pre-scaled), Kb bf16 [T][1024] ----
__global__ __launch_bounds__(256) void k_norm_rope(const float* __restrict__ qkv,
                                                   const float* __restrict__ qw,
                                                   const float* __restrict__ kw,
                                                   const float* __restrict__ cosT,
                                                   const float* __restrict__ sinT,
                                                   unsigned short* __restrict__ Qb,
                                                   unsigned short* __restrict__ Kb) {
  const int t = blockIdx.x;
  const int wid = threadIdx.x >> 6, lane = threadIdx.x & 63;
  const float* row = qkv + (size_t)t * NQKV;
  const float c1 = cosT[t * DH + lane],      s1 = sinT[t * DH + lane];
  const float c2 = cosT[t * DH + 64 + lane], s2 = sinT[t * DH + 64 + lane];
  for (int hh = wid; hh < 24; hh += 4) {
    const int off = hh * DH;   // q heads: cols 0..2047 ; k heads: cols 2048..3071
    const float* x = row + off;
    const float x1 = x[lane], x2 = x[lane + 64];
    float ss = x1 * x1 + x2 * x2;
#pragma unroll
    for (int o = 32; o >= 1; o >>= 1) ss += __shfl_xor(ss, o);
    const float rinv = rsqrtf(ss * (1.f / DH) + 1e-6f);
    const float* wv = (hh < 16) ? qw : kw;
    const float y1 = x1 * rinv * wv[lane];
    const float y2 = x2 * rinv * wv[lane + 64];
    float o1 = y1 * c1 - y2 * s1;
    float o2 = y2 * c2 + y1 * s2;
    if (hh < 16) {
      o1 *= QSCALE; o2 *= QSCALE;   // fold attn scale + log2e into Q
      Qb[(size_t)t * 2048 + hh * DH + lane]      = f2bf(o1);
      Qb[(size_t)t * 2048 + hh * DH + lane + 64] = f2bf(o2);
    } else {
      Kb[(size_t)t * 1024 + (hh - 16) * DH + lane]      = f2bf(o1);
      Kb[(size_t)t * 1024 + (hh - 16) * DH + lane + 64] = f2bf(o2);
    }
  }
}

// ---- bf16 GEMM: C[M][N] fp32 = A[M][K] * Bt[N][K]^T ----
// 128x128 tile, BK=64, 4 waves; double-buffered global_load_lds with stage-first
// 2-phase schedule (raw s_barrier + manual vmcnt); XOR-swizzled LDS (via pre-swizzled
// global source, rule 21); XCD-chunked block swizzle. M tiles fixed at 16 (M=2048).
__global__ __launch_bounds__(256) void k_gemm_bt(const unsigned short* __restrict__ A,
                                                 const unsigned short* __restrict__ Bt,
                                                 float* __restrict__ C, int K, int N) {
  __shared__ unsigned short lA[2][128 * 64];
  __shared__ unsigned short lB[2][128 * 64];
  const int tid = threadIdx.x;
  const int wid = tid >> 6, lane = tid & 63;
  const int lr = lane & 15, lg = lane >> 4;
  const int wr = wid >> 1, wc = wid & 1;

  // XCD-chunked bijective swizzle (grid divisible by 8)
  int wg = blockIdx.x;
  const int q8 = gridDim.x >> 3;
  wg = (wg & 7) * q8 + (wg >> 3);
  const size_t tile_m = (size_t)(wg & 15) * 128;
  const size_t tile_n = (size_t)(wg >> 4) * 128;

  f32x4 acc[4][4];
#pragma unroll
  for (int i = 0; i < 4; i++)
#pragma unroll
    for (int j = 0; j < 4; j++) acc[i][j] = (f32x4){0.f, 0.f, 0.f, 0.f};

  // staging: per wave 4 issues x (A,B); 8 rows of 128B per issue; lane l -> row +l>>3,
  // LDS chunk l&7 (linear dest), global chunk (l&7)^(r&7) (pre-swizzled source)
  const int srow = (lane >> 3);          // 0..7
  const int schunk = lane & 7;           // 16B chunk in row
  auto stage = [&](int kb /*shorts*/, int buf) {
#pragma unroll
    for (int i = 0; i < 4; i++) {
      const int rbase = wid * 32 + i * 8;
      const int r = rbase + srow;
      const int cs = (schunk ^ (r & 7)) * 8;  // shorts
      gload_lds16(A  + (tile_m + r) * (size_t)K + kb + cs, &lA[buf][rbase * 64]);
      gload_lds16(Bt + (tile_n + r) * (size_t)K + kb + cs, &lB[buf][rbase * 64]);
    }
  };

  const int nk = K / 64;
  stage(0, 0);
  asm volatile("s_waitcnt vmcnt(0)" ::: "memory");
  __builtin_amdgcn_s_barrier();
  int cur = 0;

  for (int t = 0; t < nk; ++t) {
    if (t + 1 < nk) stage((t + 1) * 64, cur ^ 1);
#pragma unroll
    for (int kk = 0; kk < 2; kk++) {
      bf16x8 af[4], bfr[4];
#pragma unroll
      for (int mi = 0; mi < 4; mi++) {
        const int rr = wr * 64 + mi * 16 + lr;
        af[mi] = *(const bf16x8*)&lA[cur][rr * 64 + (((kk * 4 + lg) ^ (rr & 7)) * 8)];
      }
#pragma unroll
      for (int ni = 0; ni < 4; ni++) {
        const int rr = wc * 64 + ni * 16 + lr;
        bfr[ni] = *(const bf16x8*)&lB[cur][rr * 64 + (((kk * 4 + lg) ^ (rr & 7)) * 8)];
      }
#pragma unroll
      for (int mi = 0; mi < 4; mi++)
#pragma unroll
        for (int ni = 0; ni < 4; ni++)
          acc[mi][ni] = __builtin_amdgcn_mfma_f32_16x16x32_bf16(af[mi], bfr[ni], acc[mi][ni], 0, 0, 0);
    }
    asm volatile("s_waitcnt vmcnt(0)" ::: "memory");  // next tile landed (hidden under MFMA)
    __builtin_amdgcn_s_barrier();                     // all waves done reading cur
    cur ^= 1;
  }
#pragma unroll
  for (int mi = 0; mi < 4; mi++)
#pragma unroll
    for (int ni = 0; ni < 4; ni++)
#pragma unroll
      for (int r = 0; r < 4; r++)
        C[(tile_m + wr * 64 + mi * 16 + lg * 4 + r) * (size_t)N + tile_n + wc * 64 + ni * 16 + lr] =
            acc[mi][ni][r];
}

// ---- flash attention: block = (head, 64 q-rows), 4 waves; K/V staged to LDS via
//      global_load_lds (double-buffered, counted vmcnt, XOR-swizzled via pre-swizzled
//      global source); reverse iteration + rigorous decay early-exit ----
__global__ __launch_bounds__(256, 2) void k_attn(const unsigned short* __restrict__ Q,
                                                 const unsigned short* __restrict__ Kb,
                                                 const unsigned short* __restrict__ Vt,
                                                 const float* __restrict__ lb,
                                                 const float* __restrict__ lbmax,
                                                 unsigned short* __restrict__ O) {
  const int tid = threadIdx.x;
  const int wid = tid >> 6, lane = tid & 63;
  const int lr = lane & 15, lg = lane >> 4;
  const int h = blockIdx.x >> 5;      // q head
  const int qblk = blockIdx.x & 31;   // 64-row block
  const int kvh = h >> 1;             // G = 2
  const int qb = qblk * 64 + wid * 16;

  __shared__ __align__(16) unsigned short lK[2][64 * 128];   // [row][128 shorts], swizzled chunks
  __shared__ __align__(16) unsigned short lV[2][128 * 64];   // [d-row][64 shorts], swizzled chunks
  __shared__ __align__(16) unsigned short plds[4][16 * 72];
  __shared__ int exitflag[4];

  const float* lbh = lb + (size_t)kvh * T_SEQ;
  const unsigned short* Kh = Kb + kvh * DH;
  const unsigned short* Vh = Vt + (size_t)kvh * DH * T_SEQ;
  const float lbmx = lbmax[kvh];
  unsigned short* myp = plds[wid];

  // Q fragments (Q pre-scaled by 1/sqrt(D)*log2e)
  bf16x8 qf[4];
  {
    const unsigned short* Qp = Q + (size_t)(qb + lr) * 2048 + h * DH + lg * 8;
#pragma unroll
    for (int kc = 0; kc < 4; kc++) qf[kc] = *(const bf16x8*)(Qp + kc * 32);
  }

  f32x4 o[8];
#pragma unroll
  for (int nc = 0; nc < 8; nc++) o[nc] = (f32x4){0.f, 0.f, 0.f, 0.f};
  float m[4], lsum[4];
#pragma unroll
  for (int r = 0; r < 4; r++) { m[r] = -1e30f; lsum[r] = 0.f; }

  const int ir[4] = {qb + lg * 4, qb + lg * 4 + 1, qb + lg * 4 + 2, qb + lg * 4 + 3};
  const float fi[4] = {(float)ir[0], (float)ir[1], (float)ir[2], (float)ir[3]};

  // stage one 64-wide K/V tile into buffer buf (8 DMA ops per wave; swizzled source)
  auto stage = [&](int kb, int buf) {
#pragma unroll
    for (int q = 0; q < 4; q++) {
      const int t = wid * 4 + q;
      {  // K rows 4t..4t+3 (256B rows, 16 chunks)
        const int r = 4 * t + (lane >> 4);
        const int j = (lane & 15) ^ (r & 7);
        gload_lds16(Kh + (size_t)(kb + r) * 1024 + j * 8, &lK[buf][t * 512]);
      }
      {  // V rows 8t..8t+3.. (128B rows, 8 chunks)
        const int r = 8 * t + (lane >> 3);
        const int j = (lane & 7) ^ (r & 7);
        gload_lds16(Vh + (size_t)r * 2048 + kb + j * 8, &lV[buf][t * 512]);
      }
    }
  };

  const int nt = qblk + 1;
  int cur = 0;
  stage((nt - 1) * 64, 0);
  float lbv = lbh[(nt - 1) * 64 + lane];
  float lbn = 0.f;

  for (int kt = nt - 1; kt >= 0; --kt) {
    const int kb = kt * 64;
    if (kt > 0) {
      stage(kb - 64, cur ^ 1);
      lbn = lbh[kb - 64 + lane];
      asm volatile("s_waitcnt vmcnt(9)" ::: "memory");   // prev tile's 8 DMA + its lb done
    } else {
      asm volatile("s_waitcnt vmcnt(0)" ::: "memory");
    }
    __syncthreads();
    // ---- QK^T from lK[cur] ----
    f32x4 sfr[4];
#pragma unroll
    for (int nf = 0; nf < 4; nf++) {
      const int rr = nf * 16 + lr;
      const unsigned short* kbase = &lK[cur][rr * 128];
      f32x4 a = (f32x4){0.f, 0.f, 0.f, 0.f};
#pragma unroll
      for (int kc = 0; kc < 4; kc++) {
        const bf16x8 kf = *(const bf16x8*)&kbase[((kc * 4 + lg) ^ (rr & 7)) * 8];
        a = __builtin_amdgcn_mfma_f32_16x16x32_bf16(qf[kc], kf, a, 0, 0, 0);
      }
      sfr[nf] = a;
    }
    // ---- bias + (diagonal-tile-only) causal mask + tile row-max ----
    float lbj[4];
#pragma unroll
    for (int nf = 0; nf < 4; nf++) lbj[nf] = __shfl(lbv, nf * 16 + lr);
    float tm[4];
#pragma unroll
    for (int r = 0; r < 4; r++) tm[r] = -1e30f;
    const int last = (kt == nt - 1);
#pragma unroll
    for (int nf = 0; nf < 4; nf++) {
      const int j = kb + nf * 16 + lr;
      const float fj = (float)j;
#pragma unroll
      for (int r = 0; r < 4; r++) {
        float sv = sfr[nf][r] + lbj[nf] * (fi[r] - fj);
        if (last) sv = (j <= ir[r]) ? sv : -1e30f;
        sfr[nf][r] = sv;
        tm[r] = fmaxf(tm[r], sv);
      }
    }
#pragma unroll
    for (int off = 8; off >= 1; off >>= 1)
#pragma unroll
      for (int r = 0; r < 4; r++) tm[r] = fmaxf(tm[r], __shfl_xor(tm[r], off));
    // ---- online softmax; skip rescale when running max unchanged ----
    float nm[4];
#pragma unroll
    for (int r = 0; r < 4; r++) nm[r] = fmaxf(m[r], tm[r]);
    const int upd = (nm[0] > m[0]) | (nm[1] > m[1]) | (nm[2] > m[2]) | (nm[3] > m[3]);
    if (__any(upd)) {
#pragma unroll
      for (int r = 0; r < 4; r++) {
        const float corr = exp2f(m[r] - nm[r]);
        m[r] = nm[r];
        lsum[r] *= corr;
#pragma unroll
        for (int nc = 0; nc < 8; nc++) o[nc][r] *= corr;
      }
    }
    float rs[4];
#pragma unroll
    for (int r = 0; r < 4; r++) rs[r] = 0.f;
#pragma unroll
    for (int nf = 0; nf < 4; nf++)
#pragma unroll
      for (int r = 0; r < 4; r++) {
        const float p = exp2f(sfr[nf][r] - m[r]);
        sfr[nf][r] = p;
        rs[r] += p;
      }
#pragma unroll
    for (int off = 8; off >= 1; off >>= 1)
#pragma unroll
      for (int r = 0; r < 4; r++) rs[r] += __shfl_xor(rs[r], off);
#pragma unroll
    for (int r = 0; r < 4; r++) lsum[r] += rs[r];
    // ---- P -> per-wave LDS, read back as A-frag ----
#pragma unroll
    for (int nf = 0; nf < 4; nf++)
#pragma unroll
      for (int r = 0; r < 4; r++)
        myp[(lg * 4 + r) * 72 + nf * 16 + lr] = f2bf(sfr[nf][r]);
    const bf16x8 pa0 = *(const bf16x8*)&myp[lr * 72 + lg * 8];
    const bf16x8 pa1 = *(const bf16x8*)&myp[lr * 72 + 32 + lg * 8];
    // ---- PV from lV[cur] ----
#pragma unroll
    for (int nc = 0; nc < 8; nc++) {
      const int rr = nc * 16 + lr;
      const unsigned short* vbase = &lV[cur][rr * 64];
      const bf16x8 v0 = *(const bf16x8*)&vbase[(lg ^ (rr & 7)) * 8];
      const bf16x8 v1 = *(const bf16x8*)&vbase[((4 + lg) ^ (rr & 7)) * 8];
      o[nc] = __builtin_amdgcn_mfma_f32_16x16x32_bf16(pa0, v0, o[nc], 0, 0, 0);
      o[nc] = __builtin_amdgcn_mfma_f32_16x16x32_bf16(pa1, v1, o[nc], 0, 0, 0);
    }
    // ---- rigorous early exit: remaining score <= 16.5 + lbmax*(i-kb+1) ----
    int ok = 1;
    const float fkb = (float)kb;
#pragma unroll
    for (int r = 0; r < 4; r++)
      ok &= (16.5f + lbmx * (fi[r] - fkb + 1.0f) < m[r] - 25.0f) ? 1 : 0;
    const int wall = __all(ok) ? 1 : 0;
    if (lane == 0) exitflag[wid] = wall;
    __syncthreads();   // also: all waves done reading buf[cur^1]'s predecessor
    if (exitflag[0] && exitflag[1] && exitflag[2] && exitflag[3]) break;
    lbv = lbn;
    cur ^= 1;
  }
  asm volatile("s_waitcnt vmcnt(0)" ::: "memory");  // drain stray prefetch before exit
  float inv[4];
#pragma unroll
  for (int r = 0; r < 4; r++) inv[r] = 1.f / lsum[r];
#pragma unroll
  for (int nc = 0; nc < 8; nc++)
#pragma unroll
    for (int r = 0; r < 4; r++)
      O[(size_t)(qb + lg * 4 + r) * 2048 + h * DH + nc * 16 + lr] = f2bf(o[nc][r] * inv[r]);
}

extern "C" void kernel_launch(void* const* d_in, const int* in_sizes, int n_in,
                              void* d_out, int out_size, void* d_ws, size_t ws_size,
                              hipStream_t stream) {
  const float* hidden = (const float*)d_in[0];
  const float* Wq     = (const float*)d_in[1];
  const float* Wk     = (const float*)d_in[2];
  const float* Wv     = (const float*)d_in[3];
  const float* Wo     = (const float*)d_in[4];
  const float* qw     = (const float*)d_in[5];
  const float* kw     = (const float*)d_in[6];
  const float* gw     = (const float*)d_in[7];
  const float* gb     = (const float*)d_in[8];
  const float* cosT   = (const float*)d_in[9];
  const float* sinT   = (const float*)d_in[10];

  char* ws = (char*)d_ws;
  const size_t MB = (size_t)1 << 20;
  unsigned short* hbf   = (unsigned short*)(ws);              // 8 MB  bf16 hidden [2048][2048]
  unsigned short* BtQKV = (unsigned short*)(ws + 8 * MB);     // 16 MB bf16 [4096][2048]
  unsigned short* WoT   = (unsigned short*)(ws + 24 * MB);    // 8 MB  bf16 [2048][2048] Wo^T
  float*          qkv   = (float*)(ws + 32 * MB);             // 32 MB fp32 [2048][4096]
  unsigned short* Qb    = (unsigned short*)(ws + 64 * MB);    // 8 MB  bf16 [2048][2048]
  unsigned short* Kbuf  = (unsigned short*)(ws + 72 * MB);    // 4 MB  bf16 [2048][1024]
  unsigned short* Vt    = (unsigned short*)(ws + 76 * MB);    // 4 MB  bf16 [8][128][2048]
  unsigned short* AO    = (unsigned short*)(ws + 80 * MB);    // 8 MB  bf16 [2048][2048]
  float*          lbuf  = (float*)(ws + 88 * MB);             // 64 KB fp32 [8][2048] (log2 beta)
  float*          lbm   = (float*)(ws + 88 * MB + 65536);     // 32 B  fp32 [8]

  k_cvt<<<4096, 256, 0, stream>>>(hidden, hbf, (HID * T_SEQ) / 4);
  k_transpose_cvt<<<dim3(32, 32), 256, 0, stream>>>(Wq, BtQKV, 2048, 2048);
  k_transpose_cvt<<<dim3(32, 16), 256, 0, stream>>>(Wk, BtQKV + (size_t)2048 * 2048, 1024, 2048);
  k_transpose_cvt<<<dim3(32, 16), 256, 0, stream>>>(Wv, BtQKV + (size_t)3072 * 2048, 1024, 2048);
  k_transpose_cvt<<<dim3(32, 32), 256, 0, stream>>>(Wo, WoT, 2048, 2048);
  k_gate<<<512, 256, 0, stream>>>(hidden, gw, gb, lbuf);
  k_lbmax<<<8, 256, 0, stream>>>(lbuf, lbm);
  k_gemm_bt<<<dim3(512), 256, 0, stream>>>(hbf, BtQKV, qkv, 2048, 4096);
  k_norm_rope<<<2048, 256, 0, stream>>>(qkv, qw, kw, cosT, sinT, Qb, Kbuf);
  k_transpose_cvt<<<dim3(32, 16), 256, 0, stream>>>(qkv + 3072, Vt, 4096, 2048);
  k_attn<<<dim3(512), 256, 0, stream>>>(Qb, Kbuf, Vt, lbuf, lbm, AO);
  k_gemm_bt<<<dim3(256), 256, 0, stream>>>(AO, WoT, (float*)d_out, 2048, 2048);
}

// Round 5
// 156.347 us; speedup vs baseline: 2.4947x; 1.1315x over previous
//
#include <hip/hip_runtime.h>

// ---- constants (problem sizes fixed by reference) ----
#define T_SEQ 2048
#define HID   2048
#define HQ    16
#define HKV   8
#define DH    128
#define NQKV  4096   // HQ*DH + 2*HKV*DH

#define QSCALE (0.08838834764831845f * 1.4426950408889634f)  // 1/sqrt(128) * log2(e)

typedef __attribute__((ext_vector_type(8))) __bf16 bf16x8;
typedef __attribute__((ext_vector_type(4))) float f32x4;
typedef __attribute__((ext_vector_type(8))) unsigned short ushort8;

__device__ __forceinline__ unsigned short f2bfc(float f) {
  return __builtin_bit_cast(unsigned short, (__bf16)f);
}
__device__ __forceinline__ float bf2f(unsigned short u) {
  unsigned v = ((unsigned)u) << 16;
  return __builtin_bit_cast(float, v);
}

__device__ __forceinline__ void gload_lds16(const void* g, void* l) {
  __builtin_amdgcn_global_load_lds((const __attribute__((address_space(1))) void*)g,
                                   (__attribute__((address_space(3))) void*)l, 16, 0, 0);
}

// ---- gate (+ fused fp32->bf16 hidden convert):
//      lb[h][t] = log2(clip(sigmoid(hidden[t].gw[:,h]+gb[h]),1e-8)); hbf = bf16(hidden) ----
__global__ __launch_bounds__(256) void k_gate_cvt(const float* __restrict__ hid,
                                                  const float* __restrict__ gw,
                                                  const float* __restrict__ gb,
                                                  float* __restrict__ lb,
                                                  unsigned short* __restrict__ hbf) {
  const int t = blockIdx.x * 4 + (threadIdx.x >> 6);
  const int lane = threadIdx.x & 63;
  float acc[8];
#pragma unroll
  for (int h = 0; h < 8; h++) acc[h] = 0.f;
  const float* hrow = hid + (size_t)t * HID;
  unsigned short* brow = hbf + (size_t)t * HID;
  for (int i = lane * 4; i < HID; i += 256) {
    const float4 hv = *(const float4*)(hrow + i);
    unsigned long long pk = (unsigned long long)f2bfc(hv.x)
                          | ((unsigned long long)f2bfc(hv.y) << 16)
                          | ((unsigned long long)f2bfc(hv.z) << 32)
                          | ((unsigned long long)f2bfc(hv.w) << 48);
    *(unsigned long long*)(brow + i) = pk;
    const float ve[4] = {hv.x, hv.y, hv.z, hv.w};
#pragma unroll
    for (int e = 0; e < 4; e++) {
      const float v = ve[e];
      const float4 a = *(const float4*)(gw + (size_t)(i + e) * 8);
      const float4 b = *(const float4*)(gw + (size_t)(i + e) * 8 + 4);
      acc[0] += v * a.x; acc[1] += v * a.y; acc[2] += v * a.z; acc[3] += v * a.w;
      acc[4] += v * b.x; acc[5] += v * b.y; acc[6] += v * b.z; acc[7] += v * b.w;
    }
  }
#pragma unroll
  for (int off = 32; off >= 1; off >>= 1)
#pragma unroll
    for (int h = 0; h < 8; h++) acc[h] += __shfl_xor(acc[h], off);
  if (lane == 0) {
#pragma unroll
    for (int h = 0; h < 8; h++) {
      const float x = acc[h] + gb[h];
      const float beta = 1.f / (1.f + __expf(-x));
      lb[(size_t)h * T_SEQ + t] = log2f(fmaxf(beta, 1e-8f));   // log2 domain
    }
  }
}

// ---- per-head max of lb (for rigorous attention early-exit bound) ----
__global__ __launch_bounds__(256) void k_lbmax(const float* __restrict__ lb,
                                               float* __restrict__ lbm) {
  const int h = blockIdx.x;
  float v = -1e30f;
  for (int i = threadIdx.x; i < T_SEQ; i += 256) v = fmaxf(v, lb[(size_t)h * T_SEQ + i]);
#pragma unroll
  for (int o = 32; o >= 1; o >>= 1) v = fmaxf(v, __shfl_xor(v, o));
  __shared__ float s[4];
  if ((threadIdx.x & 63) == 0) s[threadIdx.x >> 6] = v;
  __syncthreads();
  if (threadIdx.x == 0) lbm[h] = fmaxf(fmaxf(s[0], s[1]), fmaxf(s[2], s[3]));
}

// ---- all four weight transposes (fp32 [R][C] -> bf16 [C][R]) in one launch ----
__global__ __launch_bounds__(256) void k_transpose_w(const float* __restrict__ Wq,
                                                     const float* __restrict__ Wk,
                                                     const float* __restrict__ Wv,
                                                     const float* __restrict__ Wo,
                                                     unsigned short* __restrict__ BtQKV,
                                                     unsigned short* __restrict__ WoT) {
  __shared__ float tile[64][65];
  int b = blockIdx.x;
  const float* in; unsigned short* out; int ldin;
  if (b < 1024)      { in = Wq; out = BtQKV;                          ldin = 2048; }
  else if (b < 1536) { b -= 1024; in = Wk; out = BtQKV + (size_t)2048 * 2048; ldin = 1024; }
  else if (b < 2048) { b -= 1536; in = Wv; out = BtQKV + (size_t)3072 * 2048; ldin = 1024; }
  else               { b -= 2048; in = Wo; out = WoT;                 ldin = 2048; }
  const int ldout = 2048;
  const int r0 = (b & 31) * 64, c0 = (b >> 5) * 64;
  const int tid = threadIdx.x;
  {
    const int row = tid >> 4;
    const int cf  = (tid & 15) * 4;
#pragma unroll
    for (int k = 0; k < 4; k++) {
      const int r = row + k * 16;
      float4 v = *(const float4*)(in + (size_t)(r0 + r) * ldin + c0 + cf);
      tile[r][cf + 0] = v.x; tile[r][cf + 1] = v.y;
      tile[r][cf + 2] = v.z; tile[r][cf + 3] = v.w;
    }
  }
  __syncthreads();
  {
    const int c    = tid >> 3;
    const int rseg = (tid & 7) * 8;
#pragma unroll
    for (int k = 0; k < 2; k++) {
      const int cc = c + k * 32;
      ushort8 ov;
#pragma unroll
      for (int e = 0; e < 8; e++) ov[e] = f2bfc(tile[rseg + e][cc]);
      *(ushort8*)(out + (size_t)(c0 + cc) * ldout + r0 + rseg) = ov;
    }
  }
}

// ---- bf16 [2048][1024 of ld 4096] -> bf16 [1024][2048] transpose (V) ----
__global__ __launch_bounds__(256) void k_transpose_v(const unsigned short* __restrict__ in,
                                                     unsigned short* __restrict__ out) {
  __shared__ unsigned short tile[64][72];
  const int r0 = (blockIdx.x & 31) * 64;   // t rows
  const int c0 = (blockIdx.x >> 5) * 64;   // v-dim cols
  const int tid = threadIdx.x;
  {
    const int rr = tid >> 3, cs = (tid & 7) * 8;
#pragma unroll
    for (int k = 0; k < 2; k++) {
      const int r = rr + k * 32;
      ushort8 v = *(const ushort8*)(in + (size_t)(r0 + r) * 4096 + c0 + cs);
      *(ushort8*)&tile[r][cs] = v;
    }
  }
  __syncthreads();
  {
    const int cc = tid >> 2, rseg = (tid & 3) * 16;
#pragma unroll
    for (int k = 0; k < 2; k++) {
      ushort8 ov;
#pragma unroll
      for (int e = 0; e < 8; e++) ov[e] = tile[rseg + k * 8 + e][cc];
      *(ushort8*)(out + (size_t)(c0 + cc) * 2048 + r0 + rseg + k * 8) = ov;
    }
  }
}

// ---- per-head RMSNorm + RoPE; qkv bf16 [T][4096] -> Qb bf16 [T][2048] (pre-scaled), Kb bf16 [T][1024] ----
__global__ __launch_bounds__(256) void k_norm_rope(const unsigned short* __restrict__ qkv,
                                                   const float* __restrict__ qw,
                                                   const float* __restrict__ kw,
                                                   const float* __restrict__ cosT,
                                                   const float* __restrict__ sinT,
                                                   unsigned short* __restrict__ Qb,
                                                   unsigned short* __restrict__ Kb) {
  const int t = blockIdx.x;
  const int wid = threadIdx.x >> 6, lane = threadIdx.x & 63;
  const unsigned short* row = qkv + (size_t)t * NQKV;
  const float c1 = cosT[t * DH + lane],      s1 = sinT[t * DH + lane];
  const float c2 = cosT[t * DH + 64 + lane], s2 = sinT[t * DH + 64 + lane];
  for (int hh = wid; hh < 24; hh += 4) {
    const int off = hh * DH;
    const float x1 = bf2f(row[off + lane]), x2 = bf2f(row[off + lane + 64]);
    float ss = x1 * x1 + x2 * x2;
#pragma unroll
    for (int o = 32; o >= 1; o >>= 1) ss += __shfl_xor(ss, o);
    const float rinv = rsqrtf(ss * (1.f / DH) + 1e-6f);
    const float* wv = (hh < 16) ? qw : kw;
    const float y1 = x1 * rinv * wv[lane];
    const float y2 = x2 * rinv * wv[lane + 64];
    float o1 = y1 * c1 - y2 * s1;
    float o2 = y2 * c2 + y1 * s2;
    if (hh < 16) {
      o1 *= QSCALE; o2 *= QSCALE;
      Qb[(size_t)t * 2048 + hh * DH + lane]      = f2bfc(o1);
      Qb[(size_t)t * 2048 + hh * DH + lane + 64] = f2bfc(o2);
    } else {
      Kb[(size_t)t * 1024 + (hh - 16) * DH + lane]      = f2bfc(o1);
      Kb[(size_t)t * 1024 + (hh - 16) * DH + lane + 64] = f2bfc(o2);
    }
  }
}

// ---- bf16 GEMM: C[M][N] = A[M][K] * Bt[N][K]^T ; fp32 or bf16 output ----
// 128x128 tile, BK=64, 4 waves; double-buffered global_load_lds stage-first 2-phase;
// XOR-swizzled LDS via pre-swizzled global source; XCD-chunked block swizzle.
template <int BF16OUT>
__global__ __launch_bounds__(256) void k_gemm_bt(const unsigned short* __restrict__ A,
                                                 const unsigned short* __restrict__ Bt,
                                                 void* __restrict__ Cv, int K, int N) {
  __shared__ unsigned short lA[2][128 * 64];
  __shared__ unsigned short lB[2][128 * 64];
  const int tid = threadIdx.x;
  const int wid = tid >> 6, lane = tid & 63;
  const int lr = lane & 15, lg = lane >> 4;
  const int wr = wid >> 1, wc = wid & 1;

  int wg = blockIdx.x;
  const int q8 = gridDim.x >> 3;
  wg = (wg & 7) * q8 + (wg >> 3);
  const size_t tile_m = (size_t)(wg & 15) * 128;
  const size_t tile_n = (size_t)(wg >> 4) * 128;

  f32x4 acc[4][4];
#pragma unroll
  for (int i = 0; i < 4; i++)
#pragma unroll
    for (int j = 0; j < 4; j++) acc[i][j] = (f32x4){0.f, 0.f, 0.f, 0.f};

  const int srow = (lane >> 3);
  const int schunk = lane & 7;
  auto stage = [&](int kb, int buf) {
#pragma unroll
    for (int i = 0; i < 4; i++) {
      const int rbase = wid * 32 + i * 8;
      const int r = rbase + srow;
      const int cs = (schunk ^ (r & 7)) * 8;
      gload_lds16(A  + (tile_m + r) * (size_t)K + kb + cs, &lA[buf][rbase * 64]);
      gload_lds16(Bt + (tile_n + r) * (size_t)K + kb + cs, &lB[buf][rbase * 64]);
    }
  };

  const int nk = K / 64;
  stage(0, 0);
  asm volatile("s_waitcnt vmcnt(0)" ::: "memory");
  __builtin_amdgcn_s_barrier();
  int cur = 0;

  for (int t = 0; t < nk; ++t) {
    if (t + 1 < nk) stage((t + 1) * 64, cur ^ 1);
#pragma unroll
    for (int kk = 0; kk < 2; kk++) {
      bf16x8 af[4], bfr[4];
#pragma unroll
      for (int mi = 0; mi < 4; mi++) {
        const int rr = wr * 64 + mi * 16 + lr;
        af[mi] = *(const bf16x8*)&lA[cur][rr * 64 + (((kk * 4 + lg) ^ (rr & 7)) * 8)];
      }
#pragma unroll
      for (int ni = 0; ni < 4; ni++) {
        const int rr = wc * 64 + ni * 16 + lr;
        bfr[ni] = *(const bf16x8*)&lB[cur][rr * 64 + (((kk * 4 + lg) ^ (rr & 7)) * 8)];
      }
#pragma unroll
      for (int mi = 0; mi < 4; mi++)
#pragma unroll
        for (int ni = 0; ni < 4; ni++)
          acc[mi][ni] = __builtin_amdgcn_mfma_f32_16x16x32_bf16(af[mi], bfr[ni], acc[mi][ni], 0, 0, 0);
    }
    asm volatile("s_waitcnt vmcnt(0)" ::: "memory");
    __builtin_amdgcn_s_barrier();
    cur ^= 1;
  }
#pragma unroll
  for (int mi = 0; mi < 4; mi++)
#pragma unroll
    for (int ni = 0; ni < 4; ni++)
#pragma unroll
      for (int r = 0; r < 4; r++) {
        const size_t idx = (tile_m + wr * 64 + mi * 16 + lg * 4 + r) * (size_t)N +
                           tile_n + wc * 64 + ni * 16 + lr;
        if constexpr (BF16OUT) ((unsigned short*)Cv)[idx] = f2bfc(acc[mi][ni][r]);
        else                   ((float*)Cv)[idx] = acc[mi][ni][r];
      }
}

// ---- flash attention: block = (head, 64 q-rows), 4 waves; fixed-max exp2 softmax
//      (no per-tile max/sum trees, no rescale); 1 barrier/tile; complementary-pair
//      block swizzle; rigorous decay early-exit tested every 2nd tile ----
__global__ __launch_bounds__(256, 2) void k_attn(const unsigned short* __restrict__ Q,
                                                 const unsigned short* __restrict__ Kb,
                                                 const unsigned short* __restrict__ Vt,
                                                 const float* __restrict__ lb,
                                                 const float* __restrict__ lbmax,
                                                 unsigned short* __restrict__ O) {
  const int tid = threadIdx.x;
  const int wid = tid >> 6, lane = tid & 63;
  const int lr = lane & 15, lg = lane >> 4;
  // pairing swizzle: blocks u and u+256 (same CU slot pair) get complementary work
  const int u = blockIdx.x;
  const int h = u & 15;
  const int qp = (u >> 4) & 15;
  const int qblk = (u >> 8) ? (31 - qp) : qp;
  const int kvh = h >> 1;
  const int qb = qblk * 64 + wid * 16;

  __shared__ __align__(16) unsigned short lK[2][64 * 128];
  __shared__ __align__(16) unsigned short lV[2][128 * 64];
  __shared__ __align__(16) unsigned short plds[4][16 * 72];
  __shared__ int exitflag[4];

  const float* lbh = lb + (size_t)kvh * T_SEQ;
  const unsigned short* Kh = Kb + kvh * DH;
  const unsigned short* Vh = Vt + (size_t)kvh * DH * T_SEQ;
  const float lbmx = lbmax[kvh];
  unsigned short* myp = plds[wid];

  bf16x8 qf[4];
  {
    const unsigned short* Qp = Q + (size_t)(qb + lr) * 2048 + h * DH + lg * 8;
#pragma unroll
    for (int kc = 0; kc < 4; kc++) qf[kc] = *(const bf16x8*)(Qp + kc * 32);
  }

  f32x4 o[8];
#pragma unroll
  for (int nc = 0; nc < 8; nc++) o[nc] = (f32x4){0.f, 0.f, 0.f, 0.f};
  float rs[4] = {0.f, 0.f, 0.f, 0.f};   // per-lane partial row sums (reduced lazily)

  const int ir[4] = {qb + lg * 4, qb + lg * 4 + 1, qb + lg * 4 + 2, qb + lg * 4 + 3};
  const float fi[4] = {(float)ir[0], (float)ir[1], (float)ir[2], (float)ir[3]};

  auto stage = [&](int kb, int buf) {
#pragma unroll
    for (int q = 0; q < 4; q++) {
      const int t = wid * 4 + q;
      {
        const int r = 4 * t + (lane >> 4);
        const int j = (lane & 15) ^ (r & 7);
        gload_lds16(Kh + (size_t)(kb + r) * 1024 + j * 8, &lK[buf][t * 512]);
      }
      {
        const int r = 8 * t + (lane >> 3);
        const int j = (lane & 7) ^ (r & 7);
        gload_lds16(Vh + (size_t)r * 2048 + kb + j * 8, &lV[buf][t * 512]);
      }
    }
  };

  const int nt = qblk + 1;
  int cur = 0;
  float lbj[4], lbn[4];
  {
    const int kb0 = (nt - 1) * 64;
    stage(kb0, 0);
#pragma unroll
    for (int nf = 0; nf < 4; nf++) lbj[nf] = lbh[kb0 + nf * 16 + lr];
  }
  asm volatile("s_waitcnt vmcnt(0)" ::: "memory");
  __syncthreads();

  for (int kt = nt - 1; kt >= 0; --kt) {
    const int kb = kt * 64;
    if (kt > 0) {
      stage(kb - 64, cur ^ 1);
#pragma unroll
      for (int nf = 0; nf < 4; nf++) lbn[nf] = lbh[kb - 64 + nf * 16 + lr];
    }
    // ---- QK^T from lK[cur] ----
    f32x4 sfr[4];
#pragma unroll
    for (int nf = 0; nf < 4; nf++) {
      const int rr = nf * 16 + lr;
      const unsigned short* kbase = &lK[cur][rr * 128];
      f32x4 a = (f32x4){0.f, 0.f, 0.f, 0.f};
#pragma unroll
      for (int kc = 0; kc < 4; kc++) {
        const bf16x8 kf = *(const bf16x8*)&kbase[((kc * 4 + lg) ^ (rr & 7)) * 8];
        a = __builtin_amdgcn_mfma_f32_16x16x32_bf16(qf[kc], kf, a, 0, 0, 0);
      }
      sfr[nf] = a;
    }
    // ---- bias + causal mask (diag tile) + fixed-max exp2; accumulate per-lane sums ----
    const int last = (kt == nt - 1);
#pragma unroll
    for (int nf = 0; nf < 4; nf++) {
      const int j = kb + nf * 16 + lr;
      const float fj = (float)j;
#pragma unroll
      for (int r = 0; r < 4; r++) {
        float sv = sfr[nf][r] + lbj[nf] * (fi[r] - fj);
        if (last) sv = (j <= ir[r]) ? sv : -1e30f;
        const float p = __builtin_amdgcn_exp2f(sv);   // bounded by 2^16.4
        sfr[nf][r] = p;
        rs[r] += p;
      }
    }
    // ---- P -> per-wave LDS, read back as A-frag ----
#pragma unroll
    for (int nf = 0; nf < 4; nf++)
#pragma unroll
      for (int r = 0; r < 4; r++)
        myp[(lg * 4 + r) * 72 + nf * 16 + lr] = f2bfc(sfr[nf][r]);
    const bf16x8 pa0 = *(const bf16x8*)&myp[lr * 72 + lg * 8];
    const bf16x8 pa1 = *(const bf16x8*)&myp[lr * 72 + 32 + lg * 8];
    // ---- PV from lV[cur] ----
#pragma unroll
    for (int nc = 0; nc < 8; nc++) {
      const int rr = nc * 16 + lr;
      const unsigned short* vbase = &lV[cur][rr * 64];
      const bf16x8 v0 = *(const bf16x8*)&vbase[(lg ^ (rr & 7)) * 8];
      const bf16x8 v1 = *(const bf16x8*)&vbase[((4 + lg) ^ (rr & 7)) * 8];
      o[nc] = __builtin_amdgcn_mfma_f32_16x16x32_bf16(pa0, v0, o[nc], 0, 0, 0);
      o[nc] = __builtin_amdgcn_mfma_f32_16x16x32_bf16(pa1, v1, o[nc], 0, 0, 0);
    }
    // ---- rigorous early exit, tested every 2nd tile:
    //      tail(row i) <= 2048 * 2^(16.4 + lbmx*(i-kb+1)); exit iff tail < 2^-14 * lsum ----
    const int dotest = ((kt & 1) == 0) && (kt > 0);
    if (dotest) {
      float t0 = rs[0], t1 = rs[1], t2 = rs[2], t3 = rs[3];
#pragma unroll
      for (int off = 8; off >= 1; off >>= 1) {
        t0 += __shfl_xor(t0, off); t1 += __shfl_xor(t1, off);
        t2 += __shfl_xor(t2, off); t3 += __shfl_xor(t3, off);
      }
      const float fkb = (float)kb;
      int ok = (__builtin_amdgcn_exp2f(41.5f + lbmx * (fi[0] - fkb + 1.f)) < t0) &
               (__builtin_amdgcn_exp2f(41.5f + lbmx * (fi[1] - fkb + 1.f)) < t1) &
               (__builtin_amdgcn_exp2f(41.5f + lbmx * (fi[2] - fkb + 1.f)) < t2) &
               (__builtin_amdgcn_exp2f(41.5f + lbmx * (fi[3] - fkb + 1.f)) < t3);
      if (lane == 0) exitflag[wid] = __all(ok) ? 1 : 0;
    }
    asm volatile("s_waitcnt vmcnt(0)" ::: "memory");  // next tile + lb landed
    __syncthreads();                                  // single barrier per tile
    if (dotest && (exitflag[0] & exitflag[1] & exitflag[2] & exitflag[3])) break;
#pragma unroll
    for (int nf = 0; nf < 4; nf++) lbj[nf] = lbn[nf];
    cur ^= 1;
  }
  asm volatile("s_waitcnt vmcnt(0)" ::: "memory");  // drain stray prefetch
  // final row-sum reduce + normalize
#pragma unroll
  for (int off = 8; off >= 1; off >>= 1)
#pragma unroll
    for (int r = 0; r < 4; r++) rs[r] += __shfl_xor(rs[r], off);
  float inv[4];
#pragma unroll
  for (int r = 0; r < 4; r++) inv[r] = 1.f / rs[r];
#pragma unroll
  for (int nc = 0; nc < 8; nc++)
#pragma unroll
    for (int r = 0; r < 4; r++)
      O[(size_t)(qb + lg * 4 + r) * 2048 + h * DH + nc * 16 + lr] = f2bfc(o[nc][r] * inv[r]);
}

extern "C" void kernel_launch(void* const* d_in, const int* in_sizes, int n_in,
                              void* d_out, int out_size, void* d_ws, size_t ws_size,
                              hipStream_t stream) {
  const float* hidden = (const float*)d_in[0];
  const float* Wq     = (const float*)d_in[1];
  const float* Wk     = (const float*)d_in[2];
  const float* Wv     = (const float*)d_in[3];
  const float* Wo     = (const float*)d_in[4];
  const float* qw     = (const float*)d_in[5];
  const float* kw     = (const float*)d_in[6];
  const float* gw     = (const float*)d_in[7];
  const float* gb     = (const float*)d_in[8];
  const float* cosT   = (const float*)d_in[9];
  const float* sinT   = (const float*)d_in[10];

  char* ws = (char*)d_ws;
  const size_t MB = (size_t)1 << 20;
  unsigned short* hbf   = (unsigned short*)(ws);              // 8 MB  bf16 hidden [2048][2048]
  unsigned short* BtQKV = (unsigned short*)(ws + 8 * MB);     // 16 MB bf16 [4096][2048]
  unsigned short* WoT   = (unsigned short*)(ws + 24 * MB);    // 8 MB  bf16 [2048][2048] Wo^T
  unsigned short* qkvb  = (unsigned short*)(ws + 32 * MB);    // 16 MB bf16 [2048][4096]
  unsigned short* Qb    = (unsigned short*)(ws + 48 * MB);    // 8 MB  bf16 [2048][2048]
  unsigned short* Kbuf  = (unsigned short*)(ws + 56 * MB);    // 4 MB  bf16 [2048][1024]
  unsigned short* Vt    = (unsigned short*)(ws + 60 * MB);    // 4 MB  bf16 [8][128][2048]
  unsigned short* AO    = (unsigned short*)(ws + 64 * MB);    // 8 MB  bf16 [2048][2048]
  float*          lbuf  = (float*)(ws + 72 * MB);             // 64 KB fp32 [8][2048] (log2 beta)
  float*          lbm   = (float*)(ws + 72 * MB + 65536);     // 32 B  fp32 [8]

  k_gate_cvt<<<512, 256, 0, stream>>>(hidden, gw, gb, lbuf, hbf);
  k_lbmax<<<8, 256, 0, stream>>>(lbuf, lbm);
  k_transpose_w<<<3072, 256, 0, stream>>>(Wq, Wk, Wv, Wo, BtQKV, WoT);
  k_gemm_bt<1><<<512, 256, 0, stream>>>(hbf, BtQKV, qkvb, 2048, 4096);
  k_norm_rope<<<2048, 256, 0, stream>>>(qkvb, qw, kw, cosT, sinT, Qb, Kbuf);
  k_transpose_v<<<512, 256, 0, stream>>>(qkvb + 3072, Vt);
  k_attn<<<512, 256, 0, stream>>>(Qb, Kbuf, Vt, lbuf, lbm, AO);
  k_gemm_bt<0><<<256, 256, 0, stream>>>(AO, WoT, (float*)d_out, 2048, 2048);
}